// Round 9
// baseline (4725.222 us; speedup 1.0000x reference)
//
#include <hip/hip_runtime.h>

#define N_NODES 100000
#define N_EDGES 800000
#define HDIM 100
#define LDP 104          // plane row stride (ushorts), 8-aligned, 16B-aligned rows

typedef __attribute__((ext_vector_type(8))) short bf16x8;
typedef __attribute__((ext_vector_type(4))) float f32x4;

__device__ inline void split8(float4 a, float4 b, bf16x8& h8, bf16x8& l8) {
    float v[8] = {a.x, a.y, a.z, a.w, b.x, b.y, b.z, b.w};
    bf16x8 hh, ll;
#pragma unroll
    for (int i = 0; i < 8; ++i) {
        uint u = __float_as_uint(v[i]);
        hh[i] = (short)(u >> 16);
        float r = v[i] - __uint_as_float(u & 0xFFFF0000u);
        ll[i] = (short)(__float_as_uint(r) >> 16);
    }
    h8 = hh; l8 = ll;
}
__device__ inline float recf(ushort h, ushort l) {
    return __uint_as_float((uint)h << 16) + __uint_as_float((uint)l << 16);
}
__device__ inline ushort2 splitf(float v) {
    uint u = __float_as_uint(v);
    float r = v - __uint_as_float(u & 0xFFFF0000u);
    return make_ushort2((ushort)(u >> 16), (ushort)(__float_as_uint(r) >> 16));
}

// ---------- weight packing: fp32 [b][K][NC] -> bf16 hi/lo planes, transposed [b][NCpad][Kpad]
// CONCAT: virtual k = seg*128 + off (segments of 100 padded to 128)
template<int CONCAT>
__global__ __launch_bounds__(256)
void pack_k(const float* __restrict__ W, ushort* __restrict__ hi, ushort* __restrict__ lo,
            int K, int NC, int Kpad, int NCpad, int total)
{
    int idx = blockIdx.x * 256 + threadIdx.x;
    if (idx >= total) return;
    int per = NCpad * Kpad;
    int b = idx / per, rem = idx - b * per;
    int col = rem / Kpad, kv = rem - col * Kpad;
    int srck; bool valid;
    if (CONCAT) {
        int seg = kv >> 7, off = kv & 127;
        srck = seg * 100 + off;
        valid = (off < 100) && (srck < K) && (col < NC);
    } else {
        srck = kv;
        valid = (kv < K) && (col < NC);
    }
    float v = valid ? W[(long)b * K * NC + (long)srck * NC + col] : 0.f;
    ushort2 s = splitf(v);
    hi[idx] = s.x;
    lo[idx] = s.y;
}

// ---------- barrier-free streaming MFMA GEMM (dual-plane A or fp32 A w/ in-reg split)
// TILES*16 = NCpad, TPW tiles/wave (TILES/TPW == 4 waves). STEPS = Kpad/32.
// MODE: 0 store, 1 relu, 2 C += 0.5*(v+bias). GATHER: 0 plain, 1 concat(h[g0],h[g1],e),
// 2 concat+relu(h segs), 3 row remap via g0 (fp32 A). AFP32: A is fp32 (split in-reg).
// OUTF32: write fp32 C; else dual planes. CLAMP: zero fragments with in-row k>=104.
template<int TILES, int TPW, int STEPS, int MODE, int GATHER, int AFP32, int OUTF32, int CLAMP>
__global__ __launch_bounds__(256, 2)
void gemm8_k(const ushort* __restrict__ aHp, const ushort* __restrict__ aLp, int lda,
             const float* __restrict__ aF, int ldaf,
             const ushort* __restrict__ wH, const ushort* __restrict__ wL,
             const float* __restrict__ bias,
             float* __restrict__ Cf, ushort* __restrict__ cH, ushort* __restrict__ cL, int ldc,
             int M, int NC,
             const int* __restrict__ g0, const int* __restrict__ g1,
             const ushort* __restrict__ hHp, const ushort* __restrict__ hLp,
             const ushort* __restrict__ eHp, const ushort* __restrict__ eLp)
{
    constexpr int KPADW = STEPS * 32;
    const int tid  = threadIdx.x;
    const int lane = tid & 63;
    const int w    = tid >> 6;
    const int cl   = lane & 15;
    const int kgrp = lane >> 4;
    const long row0 = (long)blockIdx.x * 64;

    int arows[4], rs[4], rd[4];
#pragma unroll
    for (int rg = 0; rg < 4; ++rg) {
        long grow = row0 + rg * 16 + cl;
        int gc = (int)((grow < M) ? grow : (M - 1));
        arows[rg] = gc;
        if (GATHER == 1 || GATHER == 2) { rs[rg] = g0[gc]; rd[rg] = g1[gc]; }
        if (GATHER == 3) arows[rg] = g0[gc];
    }

    const bf16x8 z8 = (bf16x8){0,0,0,0,0,0,0,0};
    bf16x8 aHr[2][4], aLr[2][4], bhr[2][TPW], blr[2][TPW];
    f32x4 acc[TPW][4];
#pragma unroll
    for (int tp = 0; tp < TPW; ++tp)
#pragma unroll
        for (int rg = 0; rg < 4; ++rg) acc[tp][rg] = (f32x4){0.f, 0.f, 0.f, 0.f};

    auto loadA = [&](int st, int sl) {
        const int kgo = kgrp * 8;
#pragma unroll
        for (int rg = 0; rg < 4; ++rg) {
            if (AFP32) {
                int kk = st * 32 + kgo;
                const float* p = aF + (size_t)arows[rg] * ldaf + kk;
                float4 u0 = *(const float4*)p;
                float4 u1 = *(const float4*)(p + 4);
                split8(u0, u1, aHr[sl][rg], aLr[sl][rg]);
            } else if (GATHER == 1 || GATHER == 2) {
                int seg = st >> 2;
                int inseg = (st & 3) * 32 + kgo;
                bool ok = !CLAMP || ((st & 3) != 3) || (kgrp == 0);
                const ushort* pH = (seg == 2) ? eHp : hHp;
                const ushort* pL = (seg == 2) ? eLp : hLp;
                int row = (seg == 0) ? rs[rg] : (seg == 1) ? rd[rg] : arows[rg];
                bf16x8 h8 = z8, l8 = z8;
                if (ok) {
                    h8 = *(const bf16x8*)(pH + (size_t)row * LDP + inseg);
                    l8 = *(const bf16x8*)(pL + (size_t)row * LDP + inseg);
                }
                if (GATHER == 2 && seg < 2) {
                    bf16x8 m = h8 >> 15;      // per-element sign mask (arith shift)
                    h8 = h8 & ~m;
                    l8 = l8 & ~m;
                }
                aHr[sl][rg] = h8; aLr[sl][rg] = l8;
            } else {
                int inseg = st * 32 + kgo;
                bool ok = !CLAMP || ((st & 3) != 3) || (kgrp == 0);
                if (ok) {
                    aHr[sl][rg] = *(const bf16x8*)(aHp + (size_t)arows[rg] * lda + inseg);
                    aLr[sl][rg] = *(const bf16x8*)(aLp + (size_t)arows[rg] * lda + inseg);
                } else { aHr[sl][rg] = z8; aLr[sl][rg] = z8; }
            }
        }
    };
    auto loadB = [&](int st, int sl) {
        int kkb = st * 32 + kgrp * 8;
#pragma unroll
        for (int tp = 0; tp < TPW; ++tp) {
            int colw = (w * TPW + tp) * 16 + cl;
            bhr[sl][tp] = *(const bf16x8*)(wH + (size_t)colw * KPADW + kkb);
            blr[sl][tp] = *(const bf16x8*)(wL + (size_t)colw * KPADW + kkb);
        }
    };

    loadA(0, 0); loadB(0, 0);
    if (STEPS > 1) { loadA(1, 1); loadB(1, 1); }

#pragma unroll
    for (int st = 0; st < STEPS; ++st) {
        const int sl = st & 1;
#pragma unroll
        for (int rg = 0; rg < 4; ++rg)
#pragma unroll
            for (int tp = 0; tp < TPW; ++tp) {
                acc[tp][rg] = __builtin_amdgcn_mfma_f32_16x16x32_bf16(aLr[sl][rg], bhr[sl][tp], acc[tp][rg], 0, 0, 0);
                acc[tp][rg] = __builtin_amdgcn_mfma_f32_16x16x32_bf16(aHr[sl][rg], blr[sl][tp], acc[tp][rg], 0, 0, 0);
                acc[tp][rg] = __builtin_amdgcn_mfma_f32_16x16x32_bf16(aHr[sl][rg], bhr[sl][tp], acc[tp][rg], 0, 0, 0);
            }
        if (st + 2 < STEPS) { loadA(st + 2, sl); loadB(st + 2, sl); }
    }

    // epilogue: C/D layout col=lane&15, row=(lane>>4)*4+i
#pragma unroll
    for (int tp = 0; tp < TPW; ++tp) {
        int col = (w * TPW + tp) * 16 + cl;
        if (col >= (OUTF32 ? NC : ldc)) continue;
        float bv = (col < NC) ? bias[col] : 0.f;
#pragma unroll
        for (int rg = 0; rg < 4; ++rg) {
#pragma unroll
            for (int i = 0; i < 4; ++i) {
                long grow = row0 + rg * 16 + (lane >> 4) * 4 + i;
                if (grow >= M) continue;
                float base = (col < NC) ? (acc[tp][rg][i] + bv) : 0.f;
                long o = grow * (long)ldc + col;
                if (OUTF32) {
                    if (MODE == 1) base = fmaxf(base, 0.f);
                    Cf[o] = base;
                } else {
                    float v;
                    if (MODE == 2) v = recf(cH[o], cL[o]) + 0.5f * base;
                    else if (MODE == 1) v = fmaxf(base, 0.f);
                    else v = base;
                    ushort2 s = splitf(v);
                    cH[o] = s.x; cL[o] = s.y;
                }
            }
        }
    }
}

// ---------- fused final: out = relu(f1 @ mw2 + mb2) @ mw3 + mb3, scattered to original order
__global__ __launch_bounds__(256, 2)
void final9_k(const ushort* __restrict__ f1H, const ushort* __restrict__ f1L,  // [E][64] planes
              const ushort* __restrict__ m2H, const ushort* __restrict__ m2L,  // [32][64]
              const float* __restrict__ mb2, const float* __restrict__ mw3,
              const float* __restrict__ mb3,
              const int* __restrict__ eidx, float* __restrict__ out)
{
    const int tid = threadIdx.x, lane = tid & 63, w = tid >> 6;
    const int c = lane & 15, kgrp = lane >> 4;
    const long row0 = (long)blockIdx.x * 64;

    bf16x8 bH[2][2], bL[2][2];
#pragma unroll
    for (int t = 0; t < 2; ++t)
#pragma unroll
        for (int st = 0; st < 2; ++st) {
            long o = (long)(t * 16 + c) * 64 + st * 32 + kgrp * 8;
            bH[t][st] = *(const bf16x8*)(m2H + o);
            bL[t][st] = *(const bf16x8*)(m2L + o);
        }
    const float bias0 = mb2[c];
    const float bias1 = (c + 16 < 25) ? mb2[c + 16] : 0.f;
    const float w3a0 = mw3[c * 2 + 0], w3a1 = mw3[c * 2 + 1];
    const float w3b0 = (c + 16 < 25) ? mw3[(c + 16) * 2 + 0] : 0.f;
    const float w3b1 = (c + 16 < 25) ? mw3[(c + 16) * 2 + 1] : 0.f;
    const float b30 = mb3[0], b31 = mb3[1];

    const long arow = row0 + w * 16 + c;
    f32x4 a0 = (f32x4){0.f, 0.f, 0.f, 0.f}, a1 = a0;
#pragma unroll
    for (int st = 0; st < 2; ++st) {
        long o = arow * 64 + st * 32 + kgrp * 8;
        bf16x8 aH = *(const bf16x8*)(f1H + o);
        bf16x8 aL = *(const bf16x8*)(f1L + o);
        a0 = __builtin_amdgcn_mfma_f32_16x16x32_bf16(aL, bH[0][st], a0, 0, 0, 0);
        a0 = __builtin_amdgcn_mfma_f32_16x16x32_bf16(aH, bL[0][st], a0, 0, 0, 0);
        a0 = __builtin_amdgcn_mfma_f32_16x16x32_bf16(aH, bH[0][st], a0, 0, 0, 0);
        a1 = __builtin_amdgcn_mfma_f32_16x16x32_bf16(aL, bH[1][st], a1, 0, 0, 0);
        a1 = __builtin_amdgcn_mfma_f32_16x16x32_bf16(aH, bL[1][st], a1, 0, 0, 0);
        a1 = __builtin_amdgcn_mfma_f32_16x16x32_bf16(aH, bH[1][st], a1, 0, 0, 0);
    }
#pragma unroll
    for (int i = 0; i < 4; ++i) {
        float t0 = fmaxf(a0[i] + bias0, 0.f);
        float t1 = fmaxf(a1[i] + bias1, 0.f);
        float s0 = t0 * w3a0 + t1 * w3b0;
        float s1 = t0 * w3a1 + t1 * w3b1;
#pragma unroll
        for (int d = 1; d < 16; d <<= 1) {
            s0 += __shfl_xor(s0, d, 64);
            s1 += __shfl_xor(s1, d, 64);
        }
        if (c == 0) {
            long grow = row0 + w * 16 + (lane >> 4) * 4 + i;
            int oe = eidx[grow];
            out[(long)oe * 2 + 0] = s0 + b30;
            out[(long)oe * 2 + 1] = s1 + b31;
        }
    }
}

// ---------- CSR build ----------
__global__ __launch_bounds__(256)
void hist_k(const int* __restrict__ dst, int* __restrict__ cnt)
{
    int e = blockIdx.x * 256 + threadIdx.x;
    if (e < N_EDGES) atomicAdd(&cnt[dst[e]], 1);
}

__global__ __launch_bounds__(1024)
void scan_k(const int* __restrict__ cnt, int* __restrict__ off)
{
    __shared__ int part[1024];
    const int t = threadIdx.x;
    const int per = (N_NODES + 1023) / 1024;
    const int base = t * per;
    int s = 0;
    for (int i = 0; i < per; ++i) {
        int n = base + i;
        if (n < N_NODES) s += cnt[n];
    }
    part[t] = s;
    __syncthreads();
    for (int d = 1; d < 1024; d <<= 1) {
        int v = (t >= d) ? part[t - d] : 0;
        __syncthreads();
        part[t] += v;
        __syncthreads();
    }
    int run = (t == 0) ? 0 : part[t - 1];
    for (int i = 0; i < per; ++i) {
        int n = base + i;
        if (n < N_NODES) { off[n] = run; run += cnt[n]; }
    }
    if (t == 1023) off[N_NODES] = run;
}

__global__ __launch_bounds__(256)
void fill_k(const int* __restrict__ dst, const int* __restrict__ off,
            int* __restrict__ pos, int* __restrict__ eidx)
{
    int e = blockIdx.x * 256 + threadIdx.x;
    if (e >= N_EDGES) return;
    int d = dst[e];
    int p = atomicAdd(&pos[d], 1);
    eidx[off[d] + p] = e;
}

__global__ __launch_bounds__(256)
void perm_k(const int* __restrict__ eidx, const int* __restrict__ src,
            const int* __restrict__ dst, int* __restrict__ psrc, int* __restrict__ pdst)
{
    int j = blockIdx.x * 256 + threadIdx.x;
    if (j >= N_EDGES) return;
    int e = eidx[j];
    psrc[j] = src[e];
    pdst[j] = dst[e];
}

// ---------- aggregation: agg[n] = h[n] + sum_j relu(h[psrc[j]] + tmp[j]); planes out
__global__ __launch_bounds__(256)
void agg_k(const ushort* __restrict__ hH, const ushort* __restrict__ hL,
           const float* __restrict__ tmp,
           const int* __restrict__ psrc, const int* __restrict__ off,
           ushort* __restrict__ aH, ushort* __restrict__ aL)
{
    unsigned idx = blockIdx.x * 256u + threadIdx.x;
    if (idx >= (unsigned)(N_NODES * 26)) return;
    unsigned n = idx / 26u;
    unsigned q = (idx - n * 26u) * 4u;
    long ob = (long)n * LDP + q;
    if (q >= 100) {   // pad cols 100..103
        aH[ob] = 0; aH[ob+1] = 0; aH[ob+2] = 0; aH[ob+3] = 0;
        aL[ob] = 0; aL[ob+1] = 0; aL[ob+2] = 0; aL[ob+3] = 0;
        return;
    }
    float a0, a1, a2, a3;
    {
        ushort4 hh = *(const ushort4*)(hH + ob);
        ushort4 ll = *(const ushort4*)(hL + ob);
        a0 = recf(hh.x, ll.x); a1 = recf(hh.y, ll.y);
        a2 = recf(hh.z, ll.z); a3 = recf(hh.w, ll.w);
    }
    int j0 = off[n], j1 = off[n + 1];
    for (int j = j0; j < j1; ++j) {
        long sb = (long)psrc[j] * LDP + q;
        ushort4 hh = *(const ushort4*)(hH + sb);
        ushort4 ll = *(const ushort4*)(hL + sb);
        float4 t = *(const float4*)&tmp[(long)j * HDIM + q];
        a0 += fmaxf(recf(hh.x, ll.x) + t.x, 0.f);
        a1 += fmaxf(recf(hh.y, ll.y) + t.y, 0.f);
        a2 += fmaxf(recf(hh.z, ll.z) + t.z, 0.f);
        a3 += fmaxf(recf(hh.w, ll.w) + t.w, 0.f);
    }
    ushort2 s0 = splitf(a0), s1 = splitf(a1), s2 = splitf(a2), s3 = splitf(a3);
    ushort4 rh = make_ushort4(s0.x, s1.x, s2.x, s3.x);
    ushort4 rl = make_ushort4(s0.y, s1.y, s2.y, s3.y);
    *(ushort4*)(aH + ob) = rh;
    *(ushort4*)(aL + ob) = rl;
}

__global__ __launch_bounds__(128)
void bn_stats_k(const float* __restrict__ z, float* __restrict__ stats)
{
    int c = threadIdx.x;
    if (c >= HDIM) return;
    long rows_per = (N_NODES + gridDim.x - 1) / gridDim.x;
    long r0 = (long)blockIdx.x * rows_per;
    long r1 = r0 + rows_per; if (r1 > N_NODES) r1 = N_NODES;
    float s = 0.f, s2 = 0.f;
    for (long r = r0; r < r1; ++r) {
        float v = z[r * HDIM + c];
        s += v; s2 += v * v;
    }
    atomicAdd(&stats[c], s);
    atomicAdd(&stats[HDIM + c], s2);
}

// h = (h + relu(BN(z2)))/2 on planes (cols 0..99 only; pad stays zero)
__global__ __launch_bounds__(256)
void bn_apply_k(const float* __restrict__ z2, const float* __restrict__ stats,
                const float* __restrict__ gamma, const float* __restrict__ beta,
                ushort* __restrict__ hH, ushort* __restrict__ hL)
{
    unsigned idx = blockIdx.x * 256u + threadIdx.x;
    if (idx >= (unsigned)(N_NODES * 25)) return;
    unsigned n = idx / 25u;
    unsigned q = (idx - n * 25u) * 4u;
    const float invN = 1.f / N_NODES;
    long ob = (long)n * LDP + q;
    ushort4 hh = *(const ushort4*)(hH + ob);
    ushort4 ll = *(const ushort4*)(hL + ob);
    float4 zv = *(const float4*)&z2[(long)n * HDIM + q];
    float r[4];
    float hv[4] = {recf(hh.x, ll.x), recf(hh.y, ll.y), recf(hh.z, ll.z), recf(hh.w, ll.w)};
    float zz[4] = {zv.x, zv.y, zv.z, zv.w};
#pragma unroll
    for (int i = 0; i < 4; ++i) {
        unsigned c = q + i;
        float mu  = stats[c] * invN;
        float var = stats[HDIM + c] * invN - mu * mu;
        float v = (zz[i] - mu) * rsqrtf(var + 1e-5f) * gamma[c] + beta[c];
        r[i] = (hv[i] + fmaxf(v, 0.f)) * 0.5f;
    }
    ushort2 s0 = splitf(r[0]), s1 = splitf(r[1]), s2 = splitf(r[2]), s3 = splitf(r[3]);
    *(ushort4*)(hH + ob) = make_ushort4(s0.x, s1.x, s2.x, s3.x);
    *(ushort4*)(hL + ob) = make_ushort4(s0.y, s1.y, s2.y, s3.y);
}

static inline int gb64(long m) { return (int)((m + 63) / 64); }

extern "C" void kernel_launch(void* const* d_in, const int* in_sizes, int n_in,
                              void* d_out, int out_size, void* d_ws, size_t ws_size,
                              hipStream_t stream)
{
    const float* x         = (const float*)d_in[0];
    const int*   ei        = (const int*)  d_in[1];
    const float* edge_attr = (const float*)d_in[2];
    const float* node_w    = (const float*)d_in[3];
    const float* node_b    = (const float*)d_in[4];
    const float* edge_w    = (const float*)d_in[5];
    const float* edge_b    = (const float*)d_in[6];
    const float* lin_w     = (const float*)d_in[7];
    const float* lin_b     = (const float*)d_in[8];
    const float* w1        = (const float*)d_in[9];
    const float* b1        = (const float*)d_in[10];
    const float* w2        = (const float*)d_in[11];
    const float* b2        = (const float*)d_in[12];
    const float* gamma     = (const float*)d_in[13];
    const float* beta      = (const float*)d_in[14];
    const float* ew1       = (const float*)d_in[15];
    const float* eb1       = (const float*)d_in[16];
    const float* ew2       = (const float*)d_in[17];
    const float* eb2       = (const float*)d_in[18];
    const float* mw1       = (const float*)d_in[19];
    const float* mb1       = (const float*)d_in[20];
    const float* mw2       = (const float*)d_in[21];
    const float* mb2       = (const float*)d_in[22];
    const float* mw3       = (const float*)d_in[23];
    const float* mb3       = (const float*)d_in[24];
    float* out = (float*)d_out;

    // ---- workspace: [0,2MB) packed weights | [2MB,16MB) ints+stats | [16MB,...) activations
    ushort* pw = (ushort*)d_ws;
    size_t off_w = 0;
    ushort *nwH, *nwL, *ewH, *ewL, *liH, *liL, *w1H, *w1L, *w2H, *w2L,
           *e1H, *e1L, *e2H, *e2L, *m1H, *m1L, *m2H, *m2L;
    auto nextw = [&](size_t s, ushort*& H, ushort*& L) { H = pw + off_w; L = pw + off_w + s; off_w += 2 * s; };
    nextw(128 * 128,     nwH, nwL);   // node_w  Kpad 128
    nextw(128 * 64,      ewH, ewL);   // edge_w  Kpad 64
    nextw(2 * 128 * 128, liH, liL);
    nextw(2 * 128 * 128, w1H, w1L);
    nextw(2 * 128 * 128, w2H, w2L);
    nextw(2 * 128 * 384, e1H, e1L);   // ew1 concat Kpad 384
    nextw(2 * 128 * 128, e2H, e2L);
    nextw(64 * 384,      m1H, m1L);   // mw1 concat, NCpad 64
    nextw(32 * 64,       m2H, m2L);   // mw2 Kpad 64, NCpad 32

    int* intb = (int*)((char*)d_ws + (2u << 20));
    int* cnt   = intb;                 // N
    int* coff  = cnt + N_NODES;        // N+1
    int* pos   = coff + N_NODES + 1;   // N
    int* eidx  = pos + N_NODES;        // E
    int* psrc  = eidx + N_EDGES;       // E
    int* pdst  = psrc + N_EDGES;       // E
    float* stats = (float*)(pdst + N_EDGES);  // 256

    char* fbase = (char*)d_ws + (16u << 20);
    ushort* eHp  = (ushort*)fbase;                                 // E*104
    ushort* eLp  = eHp + (size_t)N_EDGES * LDP;                    // E*104
    ushort* hHp  = eLp + (size_t)N_EDGES * LDP;                    // N*104
    ushort* hLp  = hHp + (size_t)N_NODES * LDP;
    ushort* agH  = hLp + (size_t)N_NODES * LDP;
    ushort* agL  = agH + (size_t)N_NODES * LDP;
    char*  big   = (char*)(agL + (size_t)N_NODES * LDP);           // 320MB + guard
    float* tmp   = (float*)big;                                    // E*100 fp32 (messages / tmp2)
    ushort* zHp  = (ushort*)big;                                   // z planes (after tmp dead)
    ushort* zLp  = zHp + (size_t)N_NODES * LDP;
    float* z2    = (float*)(big + 42u * 1024 * 1024);              // N*100 fp32
    ushort* f1H  = (ushort*)big;                                   // E*64 planes (after tmp2 dead)
    ushort* f1L  = f1H + (size_t)N_EDGES * 64;

    const int* srcp = ei;
    const int* dstp = ei + N_EDGES;
    dim3 blk(256);

    // guard zeros after tmp/tmp2 end (fp32-A over-read of last row must be finite)
    hipMemsetAsync(big + (size_t)N_EDGES * HDIM * 4, 0, 512, stream);

    // ---- pack weights ----
    auto packl = [&](const float* W, ushort* H, ushort* L, int K, int NC, int Kp, int NCp, int batch, bool cc) {
        int total = batch * NCp * Kp;
        if (cc) pack_k<1><<<(total + 255) / 256, blk, 0, stream>>>(W, H, L, K, NC, Kp, NCp, total);
        else    pack_k<0><<<(total + 255) / 256, blk, 0, stream>>>(W, H, L, K, NC, Kp, NCp, total);
    };
    packl(node_w, nwH, nwL, 128, 100, 128, 128, 1, false);
    packl(edge_w, ewH, ewL,  64, 100,  64, 128, 1, false);
    packl(lin_w,  liH, liL, 100, 100, 128, 128, 2, false);
    packl(w1,     w1H, w1L, 100, 100, 128, 128, 2, false);
    packl(w2,     w2H, w2L, 100, 100, 128, 128, 2, false);
    packl(ew1,    e1H, e1L, 300, 100, 384, 128, 2, true);
    packl(ew2,    e2H, e2L, 100, 100, 128, 128, 2, false);
    packl(mw1,    m1H, m1L, 300,  50, 384,  64, 1, true);
    packl(mw2,    m2H, m2L,  50,  25,  64,  32, 1, false);

    // ---- CSR build + permuted endpoints (graph static) ----
    hipMemsetAsync(cnt, 0, N_NODES * sizeof(int), stream);
    hist_k<<<(N_EDGES + 255) / 256, blk, 0, stream>>>(dstp, cnt);
    scan_k<<<1, dim3(1024), 0, stream>>>(cnt, coff);
    hipMemsetAsync(pos, 0, N_NODES * sizeof(int), stream);
    fill_k<<<(N_EDGES + 255) / 256, blk, 0, stream>>>(dstp, coff, pos, eidx);
    perm_k<<<(N_EDGES + 255) / 256, blk, 0, stream>>>(eidx, srcp, dstp, psrc, pdst);

    // 1. h = x @ node_w + node_b   (fp32 A, K=128)  -> h planes
    gemm8_k<8,2,4,0,0,1,0,0><<<gb64(N_NODES), blk, 0, stream>>>(
        nullptr, nullptr, 0, x, 128, nwH, nwL, node_b,
        nullptr, hHp, hLp, LDP, N_NODES, 100,
        nullptr, nullptr, nullptr, nullptr, nullptr, nullptr);
    // 2. e[j] = edge_attr[eidx[j]] @ edge_w + edge_b  (fp32 A gather, K=64) -> e planes
    gemm8_k<8,2,2,0,3,1,0,0><<<gb64(N_EDGES), blk, 0, stream>>>(
        nullptr, nullptr, 0, edge_attr, 64, ewH, ewL, edge_b,
        nullptr, eHp, eLp, LDP, N_EDGES, 100,
        eidx, nullptr, nullptr, nullptr, nullptr, nullptr);

    for (int i = 0; i < 2; ++i) {
        // 3. tmp = e @ lin_w[i] + lin_b[i]  (planes A, CLAMP) -> fp32
        gemm8_k<8,2,4,0,0,0,1,1><<<gb64(N_EDGES), blk, 0, stream>>>(
            eHp, eLp, LDP, nullptr, 0, liH + (size_t)i * 16384, liL + (size_t)i * 16384, lin_b + i * HDIM,
            tmp, nullptr, nullptr, HDIM, N_EDGES, 100,
            nullptr, nullptr, nullptr, nullptr, nullptr, nullptr);
        // 4+5. agg = h + sum relu(h[src] + tmp)  -> agg planes
        agg_k<<<(N_NODES * 26 + 255) / 256, blk, 0, stream>>>(hHp, hLp, tmp, psrc, coff, agH, agL);
        // 6. z = relu(agg @ w1[i] + b1[i])  -> z planes  (tmp dead)
        gemm8_k<8,2,4,1,0,0,0,1><<<gb64(N_NODES), blk, 0, stream>>>(
            agH, agL, LDP, nullptr, 0, w1H + (size_t)i * 16384, w1L + (size_t)i * 16384, b1 + i * HDIM,
            nullptr, zHp, zLp, LDP, N_NODES, 100,
            nullptr, nullptr, nullptr, nullptr, nullptr, nullptr);
        // 7. z2 = z @ w2[i] + b2[i]  -> fp32
        gemm8_k<8,2,4,0,0,0,1,1><<<gb64(N_NODES), blk, 0, stream>>>(
            zHp, zLp, LDP, nullptr, 0, w2H + (size_t)i * 16384, w2L + (size_t)i * 16384, b2 + i * HDIM,
            z2, nullptr, nullptr, HDIM, N_NODES, 100,
            nullptr, nullptr, nullptr, nullptr, nullptr, nullptr);
        // 8. BN stats
        hipMemsetAsync(stats, 0, 2 * HDIM * sizeof(float), stream);
        bn_stats_k<<<1024, dim3(128), 0, stream>>>(z2, stats);
        // 9. h = (h + relu(BN(z2)))/2  on planes
        bn_apply_k<<<(N_NODES * 25 + 255) / 256, blk, 0, stream>>>(
            z2, stats, gamma + i * HDIM, beta + i * HDIM, hHp, hLp);
        // 10. tmp2 = relu(cat(h[src],h[dst],e) @ ew1[i] + eb1[i])  (concat planes) -> fp32 (z,z2 dead)
        gemm8_k<8,2,12,1,1,0,1,1><<<gb64(N_EDGES), blk, 0, stream>>>(
            nullptr, nullptr, 0, nullptr, 0, e1H + (size_t)i * 49152, e1L + (size_t)i * 49152, eb1 + i * HDIM,
            tmp, nullptr, nullptr, HDIM, N_EDGES, 100,
            psrc, pdst, hHp, hLp, eHp, eLp);
        // 11. e += 0.5*(tmp2 @ ew2[i] + eb2[i])  (fp32 A in-reg split, MODE2 on e planes)
        gemm8_k<8,2,4,2,0,1,0,0><<<gb64(N_EDGES), blk, 0, stream>>>(
            nullptr, nullptr, 0, tmp, HDIM, e2H + (size_t)i * 16384, e2L + (size_t)i * 16384, eb2 + i * HDIM,
            nullptr, eHp, eLp, LDP, N_EDGES, 100,
            nullptr, nullptr, nullptr, nullptr, nullptr, nullptr);
    }

    // 12. f1 = relu(cat(relu(h[src]),relu(h[dst]),e) @ mw1 + mb1)  -> f1 planes (tmp2 dead)
    gemm8_k<4,1,12,1,2,0,0,1><<<gb64(N_EDGES), blk, 0, stream>>>(
        nullptr, nullptr, 0, nullptr, 0, m1H, m1L, mb1,
        nullptr, f1H, f1L, 64, N_EDGES, 50,
        psrc, pdst, hHp, hLp, eHp, eLp);
    // 13+14. out[eidx[j]] = relu(f1 @ mw2 + mb2) @ mw3 + mb3
    final9_k<<<gb64(N_EDGES), blk, 0, stream>>>(
        f1H, f1L, m2H, m2L, mb2, mw3, mb3, eidx, out);
}

// Round 10
// 3859.887 us; speedup vs baseline: 1.2242x; 1.2242x over previous
//
#include <hip/hip_runtime.h>

#define N_NODES 100000
#define N_EDGES 800000
#define HDIM 100
#define LDP 112          // interleaved-word row stride (uints) = 448B, 64B-aligned rows
#define TSTR 104         // fp32 tmp/z2 row stride

typedef __attribute__((ext_vector_type(8))) short bf16x8;
typedef __attribute__((ext_vector_type(4))) float f32x4;

// ---- split/reconstruct helpers: word = (hi16<<16)|lo16, value = hi + lo (dual-bf16) ----
__device__ inline uint packsplit(float v) {
    uint u = __float_as_uint(v);
    float r = v - __uint_as_float(u & 0xFFFF0000u);
    return (u & 0xFFFF0000u) | (__float_as_uint(r) >> 16);
}
__device__ inline float recw(uint w) {
    return __uint_as_float(w & 0xFFFF0000u) + __uint_as_float(w << 16);
}
__device__ inline uint4 relu4(uint4 a) {   // zero word if value negative (sign bit = hi sign)
    a.x &= ~(uint)((int)a.x >> 31); a.y &= ~(uint)((int)a.y >> 31);
    a.z &= ~(uint)((int)a.z >> 31); a.w &= ~(uint)((int)a.w >> 31);
    return a;
}
__device__ inline void unpack16(uint4 a, uint4 b, bf16x8& h8, bf16x8& l8) {
    union { uint u[4]; bf16x8 v; } H, L;
    H.u[0] = __builtin_amdgcn_perm(a.y, a.x, 0x07060302u);
    H.u[1] = __builtin_amdgcn_perm(a.w, a.z, 0x07060302u);
    H.u[2] = __builtin_amdgcn_perm(b.y, b.x, 0x07060302u);
    H.u[3] = __builtin_amdgcn_perm(b.w, b.z, 0x07060302u);
    L.u[0] = __builtin_amdgcn_perm(a.y, a.x, 0x05040100u);
    L.u[1] = __builtin_amdgcn_perm(a.w, a.z, 0x05040100u);
    L.u[2] = __builtin_amdgcn_perm(b.y, b.x, 0x05040100u);
    L.u[3] = __builtin_amdgcn_perm(b.w, b.z, 0x05040100u);
    h8 = H.v; l8 = L.v;
}
__device__ inline void split8(float4 a, float4 b, bf16x8& h8, bf16x8& l8) {
    float v[8] = {a.x, a.y, a.z, a.w, b.x, b.y, b.z, b.w};
    bf16x8 hh, ll;
#pragma unroll
    for (int i = 0; i < 8; ++i) {
        uint u = __float_as_uint(v[i]);
        hh[i] = (short)(u >> 16);
        float r = v[i] - __uint_as_float(u & 0xFFFF0000u);
        ll[i] = (short)(__float_as_uint(r) >> 16);
    }
    h8 = hh; l8 = ll;
}

// ---------- weight packing: fp32 [b][K][NC] -> bf16 hi/lo planes transposed [b][NCpad][Kpad]
// CONCAT: virtual k = seg*128 + off (segments of 100 zero-padded to 128)
template<int CONCAT>
__global__ __launch_bounds__(256)
void pack_k(const float* __restrict__ W, ushort* __restrict__ hi, ushort* __restrict__ lo,
            int K, int NC, int Kpad, int NCpad, int total)
{
    int idx = blockIdx.x * 256 + threadIdx.x;
    if (idx >= total) return;
    int per = NCpad * Kpad;
    int b = idx / per, rem = idx - b * per;
    int col = rem / Kpad, kv = rem - col * Kpad;
    int srck; bool valid;
    if (CONCAT) {
        int seg = kv >> 7, off = kv & 127;
        srck = seg * 100 + off;
        valid = (off < 100) && (srck < K) && (col < NC);
    } else {
        srck = kv;
        valid = (kv < K) && (col < NC);
    }
    float v = valid ? W[(long)b * K * NC + (long)srck * NC + col] : 0.f;
    uint w = packsplit(v);
    hi[idx] = (ushort)(w >> 16);
    lo[idx] = (ushort)(w & 0xFFFFu);
}

// ---------- streaming MFMA GEMM: word-plane A (or fp32 A split in-reg), B planes in 2-slot regs.
// TILES*16=NCpad, TPW tiles/wave (4 waves). STEPS=Kpad/32.
// MODE: 0 store, 1 relu. GATHER: 0 plain rows, 3 rows via g0 (AFP32 only).
// AFP32: A fp32. OUTF32: C fp32 (ldc stride); else word planes. CLAMP: zero frag at (st&3)==3 && kgrp>0.
template<int TILES, int TPW, int STEPS, int MODE, int GATHER, int AFP32, int OUTF32, int CLAMP>
__global__ __launch_bounds__(256, 2)
void gemm9_k(const uint* aP, int lda, const float* __restrict__ aF, int ldaf,
             const ushort* __restrict__ wH, const ushort* __restrict__ wL,
             const float* __restrict__ bias,
             float* __restrict__ Cf, uint* cP, int ldc,
             int M, int NC, const int* __restrict__ g0)
{
    constexpr int KPADW = STEPS * 32;
    const int tid  = threadIdx.x;
    const int lane = tid & 63;
    const int w    = tid >> 6;
    const int cl   = lane & 15;
    const int kgrp = lane >> 4;
    const long row0 = (long)blockIdx.x * 64;

    int arows[4];
#pragma unroll
    for (int rg = 0; rg < 4; ++rg) {
        long grow = row0 + rg * 16 + cl;
        int gc = (int)((grow < M) ? grow : (M - 1));
        arows[rg] = (GATHER == 3) ? g0[gc] : gc;
    }

    uint4  aw0[2][4], aw1[2][4];
    float4 af0[2][4], af1[2][4];
    bf16x8 bh[2][TPW], bl[2][TPW];
    f32x4  acc[TPW][4];
#pragma unroll
    for (int tp = 0; tp < TPW; ++tp)
#pragma unroll
        for (int rg = 0; rg < 4; ++rg) acc[tp][rg] = (f32x4){0.f, 0.f, 0.f, 0.f};

    auto loadA = [&](int st, int sl) {
        const int kk = st * 32 + kgrp * 8;
#pragma unroll
        for (int rg = 0; rg < 4; ++rg) {
            if (AFP32) {
                const float* p = aF + (size_t)arows[rg] * ldaf + kk;
                af0[sl][rg] = *(const float4*)p;
                af1[sl][rg] = *(const float4*)(p + 4);
            } else {
                bool ok = !CLAMP || ((st & 3) != 3) || (kgrp == 0);
                if (ok) {
                    const uint* p = aP + (size_t)arows[rg] * lda + kk;
                    aw0[sl][rg] = *(const uint4*)p;
                    aw1[sl][rg] = *(const uint4*)(p + 4);
                } else {
                    aw0[sl][rg] = make_uint4(0, 0, 0, 0);
                    aw1[sl][rg] = make_uint4(0, 0, 0, 0);
                }
            }
        }
    };
    auto loadB = [&](int st, int sl) {
        int kk = st * 32 + kgrp * 8;
#pragma unroll
        for (int tp = 0; tp < TPW; ++tp) {
            int colw = (w * TPW + tp) * 16 + cl;
            bh[sl][tp] = *(const bf16x8*)(wH + (size_t)colw * KPADW + kk);
            bl[sl][tp] = *(const bf16x8*)(wL + (size_t)colw * KPADW + kk);
        }
    };

    loadA(0, 0); loadB(0, 0);
    if (STEPS > 1) { loadA(1, 1); loadB(1, 1); }

#pragma unroll
    for (int st = 0; st < STEPS; ++st) {
        const int sl = st & 1;
#pragma unroll
        for (int rg = 0; rg < 4; ++rg) {
            bf16x8 aH, aL;
            if (AFP32) split8(af0[sl][rg], af1[sl][rg], aH, aL);
            else       unpack16(aw0[sl][rg], aw1[sl][rg], aH, aL);
#pragma unroll
            for (int tp = 0; tp < TPW; ++tp) {
                acc[tp][rg] = __builtin_amdgcn_mfma_f32_16x16x32_bf16(aL, bh[sl][tp], acc[tp][rg], 0, 0, 0);
                acc[tp][rg] = __builtin_amdgcn_mfma_f32_16x16x32_bf16(aH, bl[sl][tp], acc[tp][rg], 0, 0, 0);
                acc[tp][rg] = __builtin_amdgcn_mfma_f32_16x16x32_bf16(aH, bh[sl][tp], acc[tp][rg], 0, 0, 0);
            }
        }
        if (st + 2 < STEPS) { loadA(st + 2, sl); loadB(st + 2, sl); }
    }

    // epilogue: C/D layout col=lane&15, row=(lane>>4)*4+i
#pragma unroll
    for (int tp = 0; tp < TPW; ++tp) {
        int col = (w * TPW + tp) * 16 + cl;
        if (col >= NC) continue;
        float bv = bias[col];
#pragma unroll
        for (int rg = 0; rg < 4; ++rg) {
#pragma unroll
            for (int i = 0; i < 4; ++i) {
                long grow = row0 + rg * 16 + kgrp * 4 + i;
                if (grow >= M) continue;
                float v = acc[tp][rg][i] + bv;
                if (MODE == 1) v = fmaxf(v, 0.f);
                long o = grow * (long)ldc + col;
                if (OUTF32) Cf[o] = v;
                else        cP[o] = packsplit(v);
            }
        }
    }
}

// ---------- fused steps 10+11: tmp2 = relu(cat(h[s],h[d],e)@ew1+b1) in LDS; e += 0.5*(tmp2@ew2+b2)
__global__ __launch_bounds__(256, 2)
void fused_edge_k(const uint* __restrict__ hP, uint* eP,
                  const ushort* __restrict__ w1H, const ushort* __restrict__ w1L,
                  const float* __restrict__ b1v,
                  const ushort* __restrict__ w2H, const ushort* __restrict__ w2L,
                  const float* __restrict__ b2v,
                  const int* __restrict__ g0, const int* __restrict__ g1)
{
    __shared__ uint sm[64 * 128];        // tmp2 tile, word planes, XOR-swizzled
    const int tid = threadIdx.x, lane = tid & 63, w = tid >> 6;
    const int cl = lane & 15, kgrp = lane >> 4;
    const long row0 = (long)blockIdx.x * 64;

    int rs[4], rd[4];
#pragma unroll
    for (int rg = 0; rg < 4; ++rg) {
        long gr = row0 + rg * 16 + cl;
        rs[rg] = g0[gr]; rd[rg] = g1[gr];
    }

    uint4 aw0[2][4], aw1[2][4];
    bf16x8 bh[2][2], bl[2][2];
    f32x4 acc[2][4];
#pragma unroll
    for (int tp = 0; tp < 2; ++tp)
#pragma unroll
        for (int rg = 0; rg < 4; ++rg) acc[tp][rg] = (f32x4){0.f, 0.f, 0.f, 0.f};

    auto loadA = [&](int st, int sl) {
        int seg = st >> 2, inseg = (st & 3) * 32 + kgrp * 8;
        bool ok = ((st & 3) != 3) || (kgrp == 0);
        const uint* base = (seg == 2) ? eP : hP;
#pragma unroll
        for (int rg = 0; rg < 4; ++rg) {
            if (ok) {
                long row = (seg == 0) ? rs[rg] : (seg == 1) ? rd[rg] : (row0 + rg * 16 + cl);
                const uint* p = base + (size_t)row * LDP + inseg;
                aw0[sl][rg] = *(const uint4*)p;
                aw1[sl][rg] = *(const uint4*)(p + 4);
            } else {
                aw0[sl][rg] = make_uint4(0, 0, 0, 0);
                aw1[sl][rg] = make_uint4(0, 0, 0, 0);
            }
        }
    };
    auto loadB = [&](int st, int sl) {
        int kk = st * 32 + kgrp * 8;
#pragma unroll
        for (int tp = 0; tp < 2; ++tp) {
            int colw = (w * 2 + tp) * 16 + cl;
            bh[sl][tp] = *(const bf16x8*)(w1H + (size_t)colw * 384 + kk);
            bl[sl][tp] = *(const bf16x8*)(w1L + (size_t)colw * 384 + kk);
        }
    };

    loadA(0, 0); loadB(0, 0); loadA(1, 1); loadB(1, 1);
#pragma unroll
    for (int st = 0; st < 12; ++st) {
        const int sl = st & 1;
#pragma unroll
        for (int rg = 0; rg < 4; ++rg) {
            bf16x8 aH, aL;
            unpack16(aw0[sl][rg], aw1[sl][rg], aH, aL);
#pragma unroll
            for (int tp = 0; tp < 2; ++tp) {
                acc[tp][rg] = __builtin_amdgcn_mfma_f32_16x16x32_bf16(aL, bh[sl][tp], acc[tp][rg], 0, 0, 0);
                acc[tp][rg] = __builtin_amdgcn_mfma_f32_16x16x32_bf16(aH, bl[sl][tp], acc[tp][rg], 0, 0, 0);
                acc[tp][rg] = __builtin_amdgcn_mfma_f32_16x16x32_bf16(aH, bh[sl][tp], acc[tp][rg], 0, 0, 0);
            }
        }
        if (st + 2 < 12) { loadA(st + 2, sl); loadB(st + 2, sl); }
    }

    // pass-1 epilogue -> LDS (stride 128, XOR swizzle col^((row&7)<<2); cols 100..127 = 0)
#pragma unroll
    for (int tp = 0; tp < 2; ++tp) {
        int col = (w * 2 + tp) * 16 + cl;
        float bv = (col < 100) ? b1v[col] : 0.f;
#pragma unroll
        for (int rg = 0; rg < 4; ++rg)
#pragma unroll
            for (int i = 0; i < 4; ++i) {
                int row = rg * 16 + kgrp * 4 + i;
                uint u = 0;
                if (col < 100) u = packsplit(fmaxf(acc[tp][rg][i] + bv, 0.f));
                sm[row * 128 + (col ^ ((row & 7) << 2))] = u;
            }
    }
    __syncthreads();

    // pass 2: acc2 = tmp2 @ ew2 (K=128 from LDS)
    f32x4 acc2[2][4];
#pragma unroll
    for (int tp = 0; tp < 2; ++tp)
#pragma unroll
        for (int rg = 0; rg < 4; ++rg) acc2[tp][rg] = (f32x4){0.f, 0.f, 0.f, 0.f};
    bf16x8 ch[2][2], clo[2][2];
    auto loadB2 = [&](int st, int sl) {
        int kk = st * 32 + kgrp * 8;
#pragma unroll
        for (int tp = 0; tp < 2; ++tp) {
            int colw = (w * 2 + tp) * 16 + cl;
            ch[sl][tp]  = *(const bf16x8*)(w2H + (size_t)colw * 128 + kk);
            clo[sl][tp] = *(const bf16x8*)(w2L + (size_t)colw * 128 + kk);
        }
    };
    loadB2(0, 0); loadB2(1, 1);
#pragma unroll
    for (int st = 0; st < 4; ++st) {
        const int sl = st & 1;
#pragma unroll
        for (int rg = 0; rg < 4; ++rg) {
            int row = rg * 16 + cl;
            int swz = (row & 7) << 2, s4 = swz & 4;
            int k = st * 32 + kgrp * 8;
            int base = row * 128 + (k ^ (swz & 24));
            uint4 q0 = *(const uint4*)&sm[base + s4];
            uint4 q1 = *(const uint4*)&sm[base + (s4 ^ 4)];
            bf16x8 aH, aL;
            unpack16(q0, q1, aH, aL);
#pragma unroll
            for (int tp = 0; tp < 2; ++tp) {
                acc2[tp][rg] = __builtin_amdgcn_mfma_f32_16x16x32_bf16(aL, ch[sl][tp], acc2[tp][rg], 0, 0, 0);
                acc2[tp][rg] = __builtin_amdgcn_mfma_f32_16x16x32_bf16(aH, clo[sl][tp], acc2[tp][rg], 0, 0, 0);
                acc2[tp][rg] = __builtin_amdgcn_mfma_f32_16x16x32_bf16(aH, ch[sl][tp], acc2[tp][rg], 0, 0, 0);
            }
        }
        if (st + 2 < 4) loadB2(st + 2, sl);
    }
    // pass-2 epilogue: e += 0.5*(acc2 + b2)   (RMW own rows only)
#pragma unroll
    for (int tp = 0; tp < 2; ++tp) {
        int col = (w * 2 + tp) * 16 + cl;
        if (col >= 100) continue;
        float bv = b2v[col];
#pragma unroll
        for (int rg = 0; rg < 4; ++rg)
#pragma unroll
            for (int i = 0; i < 4; ++i) {
                long grow = row0 + rg * 16 + kgrp * 4 + i;
                long o = grow * (long)LDP + col;
                float v = recw(eP[o]) + 0.5f * (acc2[tp][rg][i] + bv);
                eP[o] = packsplit(v);
            }
    }
}

// ---------- fused steps 12+13+14: f1 tile in LDS -> relu(f1@mw2+b2)@mw3+b3 -> out[eidx]
__global__ __launch_bounds__(256, 2)
void fused_final_k(const uint* __restrict__ hP, const uint* __restrict__ eP,
                   const ushort* __restrict__ m1H, const ushort* __restrict__ m1L,
                   const float* __restrict__ mb1,
                   const ushort* __restrict__ m2H, const ushort* __restrict__ m2L,
                   const float* __restrict__ mb2, const float* __restrict__ mw3,
                   const float* __restrict__ mb3,
                   const int* __restrict__ g0, const int* __restrict__ g1,
                   const int* __restrict__ eidx, float* __restrict__ out)
{
    __shared__ uint sm[64 * 64];
    const int tid = threadIdx.x, lane = tid & 63, w = tid >> 6;
    const int cl = lane & 15, kgrp = lane >> 4;
    const long row0 = (long)blockIdx.x * 64;

    int rs[4], rd[4];
#pragma unroll
    for (int rg = 0; rg < 4; ++rg) {
        long gr = row0 + rg * 16 + cl;
        rs[rg] = g0[gr]; rd[rg] = g1[gr];
    }

    uint4 aw0[2][4], aw1[2][4];
    bf16x8 bh[2], bl[2];
    f32x4 acc1[4];
#pragma unroll
    for (int rg = 0; rg < 4; ++rg) acc1[rg] = (f32x4){0.f, 0.f, 0.f, 0.f};

    auto loadA = [&](int st, int sl) {
        int seg = st >> 2, inseg = (st & 3) * 32 + kgrp * 8;
        bool ok = ((st & 3) != 3) || (kgrp == 0);
        const uint* base = (seg == 2) ? eP : hP;
#pragma unroll
        for (int rg = 0; rg < 4; ++rg) {
            if (ok) {
                long row = (seg == 0) ? rs[rg] : (seg == 1) ? rd[rg] : (row0 + rg * 16 + cl);
                const uint* p = base + (size_t)row * LDP + inseg;
                aw0[sl][rg] = *(const uint4*)p;
                aw1[sl][rg] = *(const uint4*)(p + 4);
            } else {
                aw0[sl][rg] = make_uint4(0, 0, 0, 0);
                aw1[sl][rg] = make_uint4(0, 0, 0, 0);
            }
        }
    };
    auto loadB = [&](int st, int sl) {
        int kk = st * 32 + kgrp * 8;
        int colw = w * 16 + cl;
        bh[sl] = *(const bf16x8*)(m1H + (size_t)colw * 384 + kk);
        bl[sl] = *(const bf16x8*)(m1L + (size_t)colw * 384 + kk);
    };

    loadA(0, 0); loadB(0, 0); loadA(1, 1); loadB(1, 1);
#pragma unroll
    for (int st = 0; st < 12; ++st) {
        const int sl = st & 1;
#pragma unroll
        for (int rg = 0; rg < 4; ++rg) {
            uint4 w0 = aw0[sl][rg], w1 = aw1[sl][rg];
            if (st < 8) { w0 = relu4(w0); w1 = relu4(w1); }   // relu on h segments only
            bf16x8 aH, aL;
            unpack16(w0, w1, aH, aL);
            acc1[rg] = __builtin_amdgcn_mfma_f32_16x16x32_bf16(aL, bh[sl], acc1[rg], 0, 0, 0);
            acc1[rg] = __builtin_amdgcn_mfma_f32_16x16x32_bf16(aH, bl[sl], acc1[rg], 0, 0, 0);
            acc1[rg] = __builtin_amdgcn_mfma_f32_16x16x32_bf16(aH, bh[sl], acc1[rg], 0, 0, 0);
        }
        if (st + 2 < 12) { loadA(st + 2, sl); loadB(st + 2, sl); }
    }

    // epilogue1 -> LDS stride 64, swizzled; cols 50..63 zero
    {
        int col = w * 16 + cl;
        float bv = (col < 50) ? mb1[col] : 0.f;
#pragma unroll
        for (int rg = 0; rg < 4; ++rg)
#pragma unroll
            for (int i = 0; i < 4; ++i) {
                int row = rg * 16 + kgrp * 4 + i;
                uint u = 0;
                if (col < 50) u = packsplit(fmaxf(acc1[rg][i] + bv, 0.f));
                sm[row * 64 + (col ^ ((row & 7) << 2))] = u;
            }
    }
    __syncthreads();

    // pass 2: out = relu(f1@mw2 + mb2) @ mw3 + mb3
    bf16x8 c2h[2][2], c2l[2][2];
#pragma unroll
    for (int t = 0; t < 2; ++t)
#pragma unroll
        for (int st = 0; st < 2; ++st) {
            long o = (long)(t * 16 + cl) * 64 + st * 32 + kgrp * 8;
            c2h[t][st] = *(const bf16x8*)(m2H + o);
            c2l[t][st] = *(const bf16x8*)(m2L + o);
        }
    const float bias0 = mb2[cl];
    const float bias1 = (cl + 16 < 25) ? mb2[cl + 16] : 0.f;
    const float w3a0 = mw3[cl * 2 + 0], w3a1 = mw3[cl * 2 + 1];
    const float w3b0 = (cl + 16 < 25) ? mw3[(cl + 16) * 2 + 0] : 0.f;
    const float w3b1 = (cl + 16 < 25) ? mw3[(cl + 16) * 2 + 1] : 0.f;
    const float b30 = mb3[0], b31 = mb3[1];

    const int row = w * 16 + cl;
    const int swz = (row & 7) << 2, s4 = swz & 4;
    f32x4 a0 = (f32x4){0.f, 0.f, 0.f, 0.f}, a1 = a0;
#pragma unroll
    for (int st = 0; st < 2; ++st) {
        int k = st * 32 + kgrp * 8;
        int base = row * 64 + (k ^ (swz & 24));
        uint4 q0 = *(const uint4*)&sm[base + s4];
        uint4 q1 = *(const uint4*)&sm[base + (s4 ^ 4)];
        bf16x8 aH, aL;
        unpack16(q0, q1, aH, aL);
        a0 = __builtin_amdgcn_mfma_f32_16x16x32_bf16(aL, c2h[0][st], a0, 0, 0, 0);
        a0 = __builtin_amdgcn_mfma_f32_16x16x32_bf16(aH, c2l[0][st], a0, 0, 0, 0);
        a0 = __builtin_amdgcn_mfma_f32_16x16x32_bf16(aH, c2h[0][st], a0, 0, 0, 0);
        a1 = __builtin_amdgcn_mfma_f32_16x16x32_bf16(aL, c2h[1][st], a1, 0, 0, 0);
        a1 = __builtin_amdgcn_mfma_f32_16x16x32_bf16(aH, c2l[1][st], a1, 0, 0, 0);
        a1 = __builtin_amdgcn_mfma_f32_16x16x32_bf16(aH, c2h[1][st], a1, 0, 0, 0);
    }
#pragma unroll
    for (int i = 0; i < 4; ++i) {
        float t0 = fmaxf(a0[i] + bias0, 0.f);
        float t1 = fmaxf(a1[i] + bias1, 0.f);
        float s0 = t0 * w3a0 + t1 * w3b0;
        float s1 = t0 * w3a1 + t1 * w3b1;
#pragma unroll
        for (int d = 1; d < 16; d <<= 1) {
            s0 += __shfl_xor(s0, d, 64);
            s1 += __shfl_xor(s1, d, 64);
        }
        if (cl == 0) {
            long grow = row0 + w * 16 + kgrp * 4 + i;
            int oe = eidx[grow];
            out[(long)oe * 2 + 0] = s0 + b30;
            out[(long)oe * 2 + 1] = s1 + b31;
        }
    }
}

// ---------- CSR build ----------
__global__ __launch_bounds__(256)
void hist_k(const int* __restrict__ dst, int* __restrict__ cnt)
{
    int e = blockIdx.x * 256 + threadIdx.x;
    if (e < N_EDGES) atomicAdd(&cnt[dst[e]], 1);
}

__global__ __launch_bounds__(1024)
void scan_k(const int* __restrict__ cnt, int* __restrict__ off)
{
    __shared__ int part[1024];
    const int t = threadIdx.x;
    const int per = (N_NODES + 1023) / 1024;
    const int base = t * per;
    int s = 0;
    for (int i = 0; i < per; ++i) {
        int n = base + i;
        if (n < N_NODES) s += cnt[n];
    }
    part[t] = s;
    __syncthreads();
    for (int d = 1; d < 1024; d <<= 1) {
        int v = (t >= d) ? part[t - d] : 0;
        __syncthreads();
        part[t] += v;
        __syncthreads();
    }
    int run = (t == 0) ? 0 : part[t - 1];
    for (int i = 0; i < per; ++i) {
        int n = base + i;
        if (n < N_NODES) { off[n] = run; run += cnt[n]; }
    }
    if (t == 1023) off[N_NODES] = run;
}

__global__ __launch_bounds__(256)
void fill_k(const int* __restrict__ dst, const int* __restrict__ off,
            int* __restrict__ pos, int* __restrict__ eidx)
{
    int e = blockIdx.x * 256 + threadIdx.x;
    if (e >= N_EDGES) return;
    int d = dst[e];
    int p = atomicAdd(&pos[d], 1);
    eidx[off[d] + p] = e;
}

__global__ __launch_bounds__(256)
void perm_k(const int* __restrict__ eidx, const int* __restrict__ src,
            const int* __restrict__ dst, int* __restrict__ psrc, int* __restrict__ pdst)
{
    int j = blockIdx.x * 256 + threadIdx.x;
    if (j >= N_EDGES) return;
    int e = eidx[j];
    psrc[j] = src[e];
    pdst[j] = dst[e];
}

// ---------- aggregation: agg[n] = h[n] + sum_j relu(h[psrc[j]] + tmp[j]); word planes
__global__ __launch_bounds__(256)
void agg_k(const uint* __restrict__ hP, const float* __restrict__ tmp,
           const int* __restrict__ psrc, const int* __restrict__ off,
           uint* __restrict__ aP)
{
    unsigned idx = blockIdx.x * 256u + threadIdx.x;
    if (idx >= (unsigned)(N_NODES * 26)) return;
    unsigned n = idx / 26u;
    unsigned q = (idx - n * 26u) * 4u;
    long ob = (long)n * LDP + q;
    if (q >= 100) {
        *(uint4*)&aP[ob] = make_uint4(0, 0, 0, 0);
        return;
    }
    uint4 hw = *(const uint4*)&hP[ob];
    float a0 = recw(hw.x), a1 = recw(hw.y), a2 = recw(hw.z), a3 = recw(hw.w);
    int j0 = off[n], j1 = off[n + 1];
    for (int j = j0; j < j1; ++j) {
        long sb = (long)psrc[j] * LDP + q;
        uint4 sw = *(const uint4*)&hP[sb];
        float4 t = *(const float4*)&tmp[(long)j * TSTR + q];
        a0 += fmaxf(recw(sw.x) + t.x, 0.f);
        a1 += fmaxf(recw(sw.y) + t.y, 0.f);
        a2 += fmaxf(recw(sw.z) + t.z, 0.f);
        a3 += fmaxf(recw(sw.w) + t.w, 0.f);
    }
    *(uint4*)&aP[ob] = make_uint4(packsplit(a0), packsplit(a1), packsplit(a2), packsplit(a3));
}

__global__ __launch_bounds__(128)
void bn_stats_k(const float* __restrict__ z, float* __restrict__ stats)
{
    int c = threadIdx.x;
    if (c >= HDIM) return;
    long rows_per = (N_NODES + gridDim.x - 1) / gridDim.x;
    long r0 = (long)blockIdx.x * rows_per;
    long r1 = r0 + rows_per; if (r1 > N_NODES) r1 = N_NODES;
    float s = 0.f, s2 = 0.f;
    for (long r = r0; r < r1; ++r) {
        float v = z[r * TSTR + c];
        s += v; s2 += v * v;
    }
    atomicAdd(&stats[c], s);
    atomicAdd(&stats[HDIM + c], s2);
}

// h = (h + relu(BN(z2)))/2 on word planes
__global__ __launch_bounds__(256)
void bn_apply_k(const float* __restrict__ z2, const float* __restrict__ stats,
                const float* __restrict__ gamma, const float* __restrict__ beta,
                uint* __restrict__ hP)
{
    unsigned idx = blockIdx.x * 256u + threadIdx.x;
    if (idx >= (unsigned)(N_NODES * 25)) return;
    unsigned n = idx / 25u;
    unsigned q = (idx - n * 25u) * 4u;
    const float invN = 1.f / N_NODES;
    long ob = (long)n * LDP + q;
    uint4 hw = *(const uint4*)&hP[ob];
    float4 zv = *(const float4*)&z2[(long)n * TSTR + q];
    float hv[4] = {recw(hw.x), recw(hw.y), recw(hw.z), recw(hw.w)};
    float zz[4] = {zv.x, zv.y, zv.z, zv.w};
    float r[4];
#pragma unroll
    for (int i = 0; i < 4; ++i) {
        unsigned c = q + i;
        float mu  = stats[c] * invN;
        float var = stats[HDIM + c] * invN - mu * mu;
        float v = (zz[i] - mu) * rsqrtf(var + 1e-5f) * gamma[c] + beta[c];
        r[i] = (hv[i] + fmaxf(v, 0.f)) * 0.5f;
    }
    *(uint4*)&hP[ob] = make_uint4(packsplit(r[0]), packsplit(r[1]), packsplit(r[2]), packsplit(r[3]));
}

static inline int gb64(long m) { return (int)((m + 63) / 64); }

extern "C" void kernel_launch(void* const* d_in, const int* in_sizes, int n_in,
                              void* d_out, int out_size, void* d_ws, size_t ws_size,
                              hipStream_t stream)
{
    const float* x         = (const float*)d_in[0];
    const int*   ei        = (const int*)  d_in[1];
    const float* edge_attr = (const float*)d_in[2];
    const float* node_w    = (const float*)d_in[3];
    const float* node_b    = (const float*)d_in[4];
    const float* edge_w    = (const float*)d_in[5];
    const float* edge_b    = (const float*)d_in[6];
    const float* lin_w     = (const float*)d_in[7];
    const float* lin_b     = (const float*)d_in[8];
    const float* w1        = (const float*)d_in[9];
    const float* b1        = (const float*)d_in[10];
    const float* w2        = (const float*)d_in[11];
    const float* b2        = (const float*)d_in[12];
    const float* gamma     = (const float*)d_in[13];
    const float* beta      = (const float*)d_in[14];
    const float* ew1       = (const float*)d_in[15];
    const float* eb1       = (const float*)d_in[16];
    const float* ew2       = (const float*)d_in[17];
    const float* eb2       = (const float*)d_in[18];
    const float* mw1       = (const float*)d_in[19];
    const float* mb1       = (const float*)d_in[20];
    const float* mw2       = (const float*)d_in[21];
    const float* mb2       = (const float*)d_in[22];
    const float* mw3       = (const float*)d_in[23];
    const float* mb3       = (const float*)d_in[24];
    float* out = (float*)d_out;

    // ---- workspace: [0,2MB) weights | [2MB,16MB) ints+stats | [16MB,..) activations
    ushort* pw = (ushort*)d_ws;
    size_t off_w = 0;
    ushort *nwH, *nwL, *ewH, *ewL, *liH, *liL, *w1H, *w1L, *w2H, *w2L,
           *e1H, *e1L, *e2H, *e2L, *m1H, *m1L, *m2H, *m2L;
    auto nextw = [&](size_t s, ushort*& H, ushort*& L) { H = pw + off_w; L = pw + off_w + s; off_w += 2 * s; };
    nextw(128 * 128,     nwH, nwL);   // node_w  Kpad 128
    nextw(128 * 64,      ewH, ewL);   // edge_w  Kpad 64
    nextw(2 * 128 * 128, liH, liL);
    nextw(2 * 128 * 128, w1H, w1L);
    nextw(2 * 128 * 128, w2H, w2L);
    nextw(2 * 128 * 384, e1H, e1L);   // ew1 concat Kpad 384
    nextw(2 * 128 * 128, e2H, e2L);
    nextw(64 * 384,      m1H, m1L);   // mw1 concat NCpad 64
    nextw(32 * 64,       m2H, m2L);   // mw2 Kpad 64 NCpad 32

    int* intb = (int*)((char*)d_ws + (2u << 20));
    int* cnt   = intb;
    int* coff  = cnt + N_NODES;
    int* pos   = coff + N_NODES + 1;
    int* eidx  = pos + N_NODES;
    int* psrc  = eidx + N_EDGES;
    int* pdst  = psrc + N_EDGES;
    float* stats = (float*)(pdst + N_EDGES);

    char* fbase = (char*)d_ws + (16u << 20);
    uint* eP = (uint*)fbase;                          // E*112 words (358.4MB)
    uint* hP = eP + (size_t)N_EDGES * LDP;            // N*112 (44.8MB)
    uint* aP = hP + (size_t)N_NODES * LDP;            // N*112 (44.8MB) (also holds z in-place)
    char* big = (char*)(aP + (size_t)N_NODES * LDP);
    float* tmp = (float*)big;                         // E*104 fp32 (332.8MB)
    float* z2  = (float*)big;                         // N*104 fp32 (aliases tmp after tmp dead)

    const int* srcp = ei;
    const int* dstp = ei + N_EDGES;
    dim3 blk(256);

    // ---- pack weights ----
    auto packl = [&](const float* W, ushort* H, ushort* L, int K, int NC, int Kp, int NCp, int batch, bool cc) {
        int total = batch * NCp * Kp;
        if (cc) pack_k<1><<<(total + 255) / 256, blk, 0, stream>>>(W, H, L, K, NC, Kp, NCp, total);
        else    pack_k<0><<<(total + 255) / 256, blk, 0, stream>>>(W, H, L, K, NC, Kp, NCp, total);
    };
    packl(node_w, nwH, nwL, 128, 100, 128, 128, 1, false);
    packl(edge_w, ewH, ewL,  64, 100,  64, 128, 1, false);
    packl(lin_w,  liH, liL, 100, 100, 128, 128, 2, false);
    packl(w1,     w1H, w1L, 100, 100, 128, 128, 2, false);
    packl(w2,     w2H, w2L, 100, 100, 128, 128, 2, false);
    packl(ew1,    e1H, e1L, 300, 100, 384, 128, 2, true);
    packl(ew2,    e2H, e2L, 100, 100, 128, 128, 2, false);
    packl(mw1,    m1H, m1L, 300,  50, 384,  64, 1, true);
    packl(mw2,    m2H, m2L,  50,  25,  64,  32, 1, false);

    // ---- CSR build (graph static) ----
    hipMemsetAsync(cnt, 0, N_NODES * sizeof(int), stream);
    hist_k<<<(N_EDGES + 255) / 256, blk, 0, stream>>>(dstp, cnt);
    scan_k<<<1, dim3(1024), 0, stream>>>(cnt, coff);
    hipMemsetAsync(pos, 0, N_NODES * sizeof(int), stream);
    fill_k<<<(N_EDGES + 255) / 256, blk, 0, stream>>>(dstp, coff, pos, eidx);
    perm_k<<<(N_EDGES + 255) / 256, blk, 0, stream>>>(eidx, srcp, dstp, psrc, pdst);

    // 1. h = x @ node_w + node_b   (fp32 A, K=128) -> hP words
    gemm9_k<8,2,4,0,0,1,0,0><<<gb64(N_NODES), blk, 0, stream>>>(
        nullptr, 0, x, 128, nwH, nwL, node_b, nullptr, hP, LDP, N_NODES, 100, nullptr);
    // 2. e[j] = edge_attr[eidx[j]] @ edge_w + edge_b  (fp32 A gather, K=64) -> eP words
    gemm9_k<8,2,2,0,3,1,0,0><<<gb64(N_EDGES), blk, 0, stream>>>(
        nullptr, 0, edge_attr, 64, ewH, ewL, edge_b, nullptr, eP, LDP, N_EDGES, 100, eidx);

    for (int i = 0; i < 2; ++i) {
        // 3. tmp = e @ lin_w[i] + lin_b[i]   (words -> fp32)
        gemm9_k<8,2,4,0,0,0,1,1><<<gb64(N_EDGES), blk, 0, stream>>>(
            eP, LDP, nullptr, 0, liH + (size_t)i * 16384, liL + (size_t)i * 16384,
            lin_b + i * HDIM, tmp, nullptr, TSTR, N_EDGES, 100, nullptr);
        // 4+5. agg = h + sum relu(h[src] + tmp)  -> aP words
        agg_k<<<(N_NODES * 26 + 255) / 256, blk, 0, stream>>>(hP, tmp, psrc, coff, aP);
        // 6. z = relu(agg @ w1[i] + b1[i])  in-place on aP (block reads own rows before writing)
        gemm9_k<8,2,4,1,0,0,0,1><<<gb64(N_NODES), blk, 0, stream>>>(
            aP, LDP, nullptr, 0, w1H + (size_t)i * 16384, w1L + (size_t)i * 16384,
            b1 + i * HDIM, nullptr, aP, LDP, N_NODES, 100, nullptr);
        // 7. z2 = z @ w2[i] + b2[i]  -> fp32 (tmp dead)
        gemm9_k<8,2,4,0,0,0,1,1><<<gb64(N_NODES), blk, 0, stream>>>(
            aP, LDP, nullptr, 0, w2H + (size_t)i * 16384, w2L + (size_t)i * 16384,
            b2 + i * HDIM, z2, nullptr, TSTR, N_NODES, 100, nullptr);
        // 8. BN stats
        hipMemsetAsync(stats, 0, 2 * HDIM * sizeof(float), stream);
        bn_stats_k<<<1024, dim3(128), 0, stream>>>(z2, stats);
        // 9. h = (h + relu(BN(z2)))/2
        bn_apply_k<<<(N_NODES * 25 + 255) / 256, blk, 0, stream>>>(
            z2, stats, gamma + i * HDIM, beta + i * HDIM, hP);
        // 10+11. fused edge update: e += 0.5*(relu(cat@ew1+b1)@ew2+b2)
        fused_edge_k<<<gb64(N_EDGES), blk, 0, stream>>>(
            hP, eP,
            e1H + (size_t)i * 49152, e1L + (size_t)i * 49152, eb1 + i * HDIM,
            e2H + (size_t)i * 16384, e2L + (size_t)i * 16384, eb2 + i * HDIM,
            psrc, pdst);
    }

    // 12+13+14. fused final MLP -> out[eidx]
    fused_final_k<<<gb64(N_EDGES), blk, 0, stream>>>(
        hP, eP, m1H, m1L, mb1, m2H, m2L, mb2, mw3, mb3, psrc, pdst, eidx, out);
}

// Round 11
// 3549.966 us; speedup vs baseline: 1.3311x; 1.0873x over previous
//
#include <hip/hip_runtime.h>

#define N_NODES 100000
#define N_EDGES 800000
#define HDIM 100
#define LDP 112          // word-plane row stride (uints) = 448B, 64B-aligned rows
#define TSTR 104         // fp32 row stride

typedef __attribute__((ext_vector_type(8))) short bf16x8;
typedef __attribute__((ext_vector_type(4))) float f32x4;

// ---- dual-bf16 word helpers: word = (hi16<<16)|lo16, value = hi + lo ----
__device__ inline uint packsplit(float v) {
    uint u = __float_as_uint(v);
    float r = v - __uint_as_float(u & 0xFFFF0000u);
    return (u & 0xFFFF0000u) | (__float_as_uint(r) >> 16);
}
__device__ inline float recw(uint w) {
    return __uint_as_float(w & 0xFFFF0000u) + __uint_as_float(w << 16);
}
__device__ inline uint4 relu4(uint4 a) {
    a.x &= ~(uint)((int)a.x >> 31); a.y &= ~(uint)((int)a.y >> 31);
    a.z &= ~(uint)((int)a.z >> 31); a.w &= ~(uint)((int)a.w >> 31);
    return a;
}
__device__ inline void unpack16(uint4 a, uint4 b, bf16x8& h8, bf16x8& l8) {
    union { uint u[4]; bf16x8 v; } H, L;
    H.u[0] = __builtin_amdgcn_perm(a.y, a.x, 0x07060302u);
    H.u[1] = __builtin_amdgcn_perm(a.w, a.z, 0x07060302u);
    H.u[2] = __builtin_amdgcn_perm(b.y, b.x, 0x07060302u);
    H.u[3] = __builtin_amdgcn_perm(b.w, b.z, 0x07060302u);
    L.u[0] = __builtin_amdgcn_perm(a.y, a.x, 0x05040100u);
    L.u[1] = __builtin_amdgcn_perm(a.w, a.z, 0x05040100u);
    L.u[2] = __builtin_amdgcn_perm(b.y, b.x, 0x05040100u);
    L.u[3] = __builtin_amdgcn_perm(b.w, b.z, 0x05040100u);
    h8 = H.v; l8 = L.v;
}
__device__ inline void split8(float4 a, float4 b, bf16x8& h8, bf16x8& l8) {
    float v[8] = {a.x, a.y, a.z, a.w, b.x, b.y, b.z, b.w};
    bf16x8 hh, ll;
#pragma unroll
    for (int i = 0; i < 8; ++i) {
        uint u = __float_as_uint(v[i]);
        hh[i] = (short)(u >> 16);
        float r = v[i] - __uint_as_float(u & 0xFFFF0000u);
        ll[i] = (short)(__float_as_uint(r) >> 16);
    }
    h8 = hh; l8 = ll;
}

// ---------- weight packing: fp32 [b][K][NC] -> bf16 hi/lo planes transposed [b][NCpad][Kpad]
template<int CONCAT>
__global__ __launch_bounds__(256)
void pack_k(const float* __restrict__ W, ushort* __restrict__ hi, ushort* __restrict__ lo,
            int K, int NC, int Kpad, int NCpad, int total)
{
    int idx = blockIdx.x * 256 + threadIdx.x;
    if (idx >= total) return;
    int per = NCpad * Kpad;
    int b = idx / per, rem = idx - b * per;
    int col = rem / Kpad, kv = rem - col * Kpad;
    int srck; bool valid;
    if (CONCAT) {
        int seg = kv >> 7, off = kv & 127;
        srck = seg * 100 + off;
        valid = (off < 100) && (srck < K) && (col < NC);
    } else {
        srck = kv;
        valid = (kv < K) && (col < NC);
    }
    float v = valid ? W[(long)b * K * NC + (long)srck * NC + col] : 0.f;
    uint w = packsplit(v);
    hi[idx] = (ushort)(w >> 16);
    lo[idx] = (ushort)(w & 0xFFFFu);
}

// ---------- streaming MFMA GEMM (word-plane A or fp32 A split in-reg), B in 2-slot regs.
// MODE: 0 store, 1 relu. GATHER: 0 plain, 3 rows via g0 (AFP32). AFP32 / OUTF32 / CLAMP as before.
template<int TILES, int TPW, int STEPS, int MODE, int GATHER, int AFP32, int OUTF32, int CLAMP>
__global__ __launch_bounds__(256, 2)
void gemm9_k(const uint* aP, int lda, const float* __restrict__ aF, int ldaf,
             const ushort* __restrict__ wH, const ushort* __restrict__ wL,
             const float* __restrict__ bias,
             float* __restrict__ Cf, uint* cP, int ldc,
             int M, int NC, const int* __restrict__ g0)
{
    constexpr int KPADW = STEPS * 32;
    const int tid  = threadIdx.x;
    const int lane = tid & 63;
    const int w    = tid >> 6;
    const int cl   = lane & 15;
    const int kgrp = lane >> 4;
    const long row0 = (long)blockIdx.x * 64;

    int arows[4];
#pragma unroll
    for (int rg = 0; rg < 4; ++rg) {
        long grow = row0 + rg * 16 + cl;
        int gc = (int)((grow < M) ? grow : (M - 1));
        arows[rg] = (GATHER == 3) ? g0[gc] : gc;
    }

    uint4  aw0[2][4], aw1[2][4];
    float4 af0[2][4], af1[2][4];
    bf16x8 bh[2][TPW], bl[2][TPW];
    f32x4  acc[TPW][4];
#pragma unroll
    for (int tp = 0; tp < TPW; ++tp)
#pragma unroll
        for (int rg = 0; rg < 4; ++rg) acc[tp][rg] = (f32x4){0.f, 0.f, 0.f, 0.f};

    auto loadA = [&](int st, int sl) {
        const int kk = st * 32 + kgrp * 8;
#pragma unroll
        for (int rg = 0; rg < 4; ++rg) {
            if (AFP32) {
                const float* p = aF + (size_t)arows[rg] * ldaf + kk;
                af0[sl][rg] = *(const float4*)p;
                af1[sl][rg] = *(const float4*)(p + 4);
            } else {
                bool ok = !CLAMP || ((st & 3) != 3) || (kgrp == 0);
                if (ok) {
                    const uint* p = aP + (size_t)arows[rg] * lda + kk;
                    aw0[sl][rg] = *(const uint4*)p;
                    aw1[sl][rg] = *(const uint4*)(p + 4);
                } else {
                    aw0[sl][rg] = make_uint4(0, 0, 0, 0);
                    aw1[sl][rg] = make_uint4(0, 0, 0, 0);
                }
            }
        }
    };
    auto loadB = [&](int st, int sl) {
        int kk = st * 32 + kgrp * 8;
#pragma unroll
        for (int tp = 0; tp < TPW; ++tp) {
            int colw = (w * TPW + tp) * 16 + cl;
            bh[sl][tp] = *(const bf16x8*)(wH + (size_t)colw * KPADW + kk);
            bl[sl][tp] = *(const bf16x8*)(wL + (size_t)colw * KPADW + kk);
        }
    };

    loadA(0, 0); loadB(0, 0);
    if (STEPS > 1) { loadA(1, 1); loadB(1, 1); }

#pragma unroll
    for (int st = 0; st < STEPS; ++st) {
        const int sl = st & 1;
#pragma unroll
        for (int rg = 0; rg < 4; ++rg) {
            bf16x8 aH, aL;
            if (AFP32) split8(af0[sl][rg], af1[sl][rg], aH, aL);
            else       unpack16(aw0[sl][rg], aw1[sl][rg], aH, aL);
#pragma unroll
            for (int tp = 0; tp < TPW; ++tp) {
                acc[tp][rg] = __builtin_amdgcn_mfma_f32_16x16x32_bf16(aL, bh[sl][tp], acc[tp][rg], 0, 0, 0);
                acc[tp][rg] = __builtin_amdgcn_mfma_f32_16x16x32_bf16(aH, bl[sl][tp], acc[tp][rg], 0, 0, 0);
                acc[tp][rg] = __builtin_amdgcn_mfma_f32_16x16x32_bf16(aH, bh[sl][tp], acc[tp][rg], 0, 0, 0);
            }
        }
        if (st + 2 < STEPS) { loadA(st + 2, sl); loadB(st + 2, sl); }
    }

#pragma unroll
    for (int tp = 0; tp < TPW; ++tp) {
        int col = (w * TPW + tp) * 16 + cl;
        if (col >= NC) continue;
        float bv = bias[col];
#pragma unroll
        for (int rg = 0; rg < 4; ++rg) {
#pragma unroll
            for (int i = 0; i < 4; ++i) {
                long grow = row0 + rg * 16 + kgrp * 4 + i;
                if (grow >= M) continue;
                float v = acc[tp][rg][i] + bv;
                if (MODE == 1) v = fmaxf(v, 0.f);
                long o = grow * (long)ldc + col;
                if (OUTF32) Cf[o] = v;
                else        cP[o] = packsplit(v);
            }
        }
    }
}

// ---------- fused steps 3+4+5: msg=relu(h[src]+e@lin_w+b) -> segmented sum by dst -> aggF (fp32)
// e is CSR-sorted so a 64-edge tile spans contiguous dst; interior nodes plain-store h+sum,
// boundary nodes atomicAdd partials onto pre-initialized aggF=h.
__global__ __launch_bounds__(256, 2)
void msg_agg_k(const uint* __restrict__ eP,
               const ushort* __restrict__ wH, const ushort* __restrict__ wL,
               const float* __restrict__ bias,
               const uint* __restrict__ hP,
               const int* __restrict__ psrc, const int* __restrict__ pdst,
               float* __restrict__ aggF)
{
    __shared__ float sm[64 * 108];
    __shared__ int sd[64];
    const int tid = threadIdx.x, lane = tid & 63, w = tid >> 6;
    const int cl = lane & 15, kgrp = lane >> 4;
    const long row0 = (long)blockIdx.x * 64;

    if (tid < 64) sd[tid] = pdst[row0 + tid];

    int sr[4][4];
#pragma unroll
    for (int rg = 0; rg < 4; ++rg)
#pragma unroll
        for (int i = 0; i < 4; ++i)
            sr[rg][i] = psrc[row0 + rg * 16 + kgrp * 4 + i];

    uint4 aw0[2][4], aw1[2][4];
    bf16x8 bh[2][2], bl[2][2];
    f32x4 acc[2][4];
#pragma unroll
    for (int tp = 0; tp < 2; ++tp)
#pragma unroll
        for (int rg = 0; rg < 4; ++rg) acc[tp][rg] = (f32x4){0.f, 0.f, 0.f, 0.f};

    auto loadA = [&](int st, int sl) {
        const int kk = st * 32 + kgrp * 8;
        bool ok = ((st & 3) != 3) || (kgrp == 0);
#pragma unroll
        for (int rg = 0; rg < 4; ++rg) {
            if (ok) {
                const uint* p = eP + (size_t)(row0 + rg * 16 + cl) * LDP + kk;
                aw0[sl][rg] = *(const uint4*)p;
                aw1[sl][rg] = *(const uint4*)(p + 4);
            } else {
                aw0[sl][rg] = make_uint4(0, 0, 0, 0);
                aw1[sl][rg] = make_uint4(0, 0, 0, 0);
            }
        }
    };
    auto loadB = [&](int st, int sl) {
        int kk = st * 32 + kgrp * 8;
#pragma unroll
        for (int tp = 0; tp < 2; ++tp) {
            int colw = (w * 2 + tp) * 16 + cl;
            bh[sl][tp] = *(const bf16x8*)(wH + (size_t)colw * 128 + kk);
            bl[sl][tp] = *(const bf16x8*)(wL + (size_t)colw * 128 + kk);
        }
    };

    loadA(0, 0); loadB(0, 0); loadA(1, 1); loadB(1, 1);
#pragma unroll
    for (int st = 0; st < 4; ++st) {
        const int sl = st & 1;
#pragma unroll
        for (int rg = 0; rg < 4; ++rg) {
            bf16x8 aH, aL;
            unpack16(aw0[sl][rg], aw1[sl][rg], aH, aL);
#pragma unroll
            for (int tp = 0; tp < 2; ++tp) {
                acc[tp][rg] = __builtin_amdgcn_mfma_f32_16x16x32_bf16(aL, bh[sl][tp], acc[tp][rg], 0, 0, 0);
                acc[tp][rg] = __builtin_amdgcn_mfma_f32_16x16x32_bf16(aH, bl[sl][tp], acc[tp][rg], 0, 0, 0);
                acc[tp][rg] = __builtin_amdgcn_mfma_f32_16x16x32_bf16(aH, bh[sl][tp], acc[tp][rg], 0, 0, 0);
            }
        }
        if (st + 2 < 4) { loadA(st + 2, sl); loadB(st + 2, sl); }
    }

    // epilogue: msg = relu(acc + bias + h[src][col]) -> LDS [64][108]
#pragma unroll
    for (int tp = 0; tp < 2; ++tp) {
        int col = (w * 2 + tp) * 16 + cl;
        if (col < 100) {
            float bv = bias[col];
#pragma unroll
            for (int rg = 0; rg < 4; ++rg)
#pragma unroll
                for (int i = 0; i < 4; ++i) {
                    int row = rg * 16 + kgrp * 4 + i;
                    float hv = recw(hP[(size_t)sr[rg][i] * LDP + col]);
                    sm[row * 108 + col] = fmaxf(acc[tp][rg][i] + bv + hv, 0.f);
                }
        }
    }
    __syncthreads();

    // segmented reduce: column scan over 64 rows
    if (tid < 100) {
        const int c = tid;
        int cur = sd[0];
        float s = 0.f;
        bool first = true;
        for (int r = 0; r < 64; ++r) {
            int d = sd[r];
            if (d != cur) {
                bool contPrev = first && (row0 > 0) && (pdst[row0 - 1] == cur);
                if (contPrev) atomicAdd(&aggF[(size_t)cur * TSTR + c], s);
                else aggF[(size_t)cur * TSTR + c] = recw(hP[(size_t)cur * LDP + c]) + s;
                first = false; s = 0.f; cur = d;
            }
            s += sm[r * 108 + c];
        }
        bool contPrev = first && (row0 > 0) && (pdst[row0 - 1] == cur);
        bool contNext = (row0 + 64 < N_EDGES) && (pdst[row0 + 64] == cur);
        if (contPrev || contNext) atomicAdd(&aggF[(size_t)cur * TSTR + c], s);
        else aggF[(size_t)cur * TSTR + c] = recw(hP[(size_t)cur * LDP + c]) + s;
    }
}

// ---------- fused steps 10+11: tmp2 = relu(cat@ew1+b1) in LDS; e += 0.5*(tmp2@ew2+b2)
__global__ __launch_bounds__(256, 2)
void fused_edge_k(const uint* __restrict__ hP, uint* eP,
                  const ushort* __restrict__ w1H, const ushort* __restrict__ w1L,
                  const float* __restrict__ b1v,
                  const ushort* __restrict__ w2H, const ushort* __restrict__ w2L,
                  const float* __restrict__ b2v,
                  const int* __restrict__ g0, const int* __restrict__ g1)
{
    __shared__ uint sm[64 * 108];        // word tile, stride 108 (12r mod 32 rotation, <=2-way)
    const int tid = threadIdx.x, lane = tid & 63, w = tid >> 6;
    const int cl = lane & 15, kgrp = lane >> 4;
    const long row0 = (long)blockIdx.x * 64;

    int rs[4], rd[4];
#pragma unroll
    for (int rg = 0; rg < 4; ++rg) {
        long gr = row0 + rg * 16 + cl;
        rs[rg] = g0[gr]; rd[rg] = g1[gr];
    }

    uint4 aw0[2][4], aw1[2][4];
    bf16x8 bh[2][2], bl[2][2];
    f32x4 acc[2][4];
#pragma unroll
    for (int tp = 0; tp < 2; ++tp)
#pragma unroll
        for (int rg = 0; rg < 4; ++rg) acc[tp][rg] = (f32x4){0.f, 0.f, 0.f, 0.f};

    auto loadA = [&](int st, int sl) {
        int seg = st >> 2, inseg = (st & 3) * 32 + kgrp * 8;
        bool ok = ((st & 3) != 3) || (kgrp == 0);
        const uint* base = (seg == 2) ? eP : hP;
#pragma unroll
        for (int rg = 0; rg < 4; ++rg) {
            if (ok) {
                long row = (seg == 0) ? rs[rg] : (seg == 1) ? rd[rg] : (row0 + rg * 16 + cl);
                const uint* p = base + (size_t)row * LDP + inseg;
                aw0[sl][rg] = *(const uint4*)p;
                aw1[sl][rg] = *(const uint4*)(p + 4);
            } else {
                aw0[sl][rg] = make_uint4(0, 0, 0, 0);
                aw1[sl][rg] = make_uint4(0, 0, 0, 0);
            }
        }
    };
    auto loadB = [&](int st, int sl) {
        int kk = st * 32 + kgrp * 8;
#pragma unroll
        for (int tp = 0; tp < 2; ++tp) {
            int colw = (w * 2 + tp) * 16 + cl;
            bh[sl][tp] = *(const bf16x8*)(w1H + (size_t)colw * 384 + kk);
            bl[sl][tp] = *(const bf16x8*)(w1L + (size_t)colw * 384 + kk);
        }
    };

    loadA(0, 0); loadB(0, 0); loadA(1, 1); loadB(1, 1);
#pragma unroll
    for (int st = 0; st < 12; ++st) {
        const int sl = st & 1;
#pragma unroll
        for (int rg = 0; rg < 4; ++rg) {
            bf16x8 aH, aL;
            unpack16(aw0[sl][rg], aw1[sl][rg], aH, aL);
#pragma unroll
            for (int tp = 0; tp < 2; ++tp) {
                acc[tp][rg] = __builtin_amdgcn_mfma_f32_16x16x32_bf16(aL, bh[sl][tp], acc[tp][rg], 0, 0, 0);
                acc[tp][rg] = __builtin_amdgcn_mfma_f32_16x16x32_bf16(aH, bl[sl][tp], acc[tp][rg], 0, 0, 0);
                acc[tp][rg] = __builtin_amdgcn_mfma_f32_16x16x32_bf16(aH, bh[sl][tp], acc[tp][rg], 0, 0, 0);
            }
        }
        if (st + 2 < 12) { loadA(st + 2, sl); loadB(st + 2, sl); }
    }

    // pass-1 epilogue -> LDS (cols<100 data, [100,108) zero, >=108 skip)
#pragma unroll
    for (int tp = 0; tp < 2; ++tp) {
        int col = (w * 2 + tp) * 16 + cl;
        if (col < 108) {
            float bv = (col < 100) ? b1v[col] : 0.f;
#pragma unroll
            for (int rg = 0; rg < 4; ++rg)
#pragma unroll
                for (int i = 0; i < 4; ++i) {
                    int row = rg * 16 + kgrp * 4 + i;
                    uint u = 0;
                    if (col < 100) u = packsplit(fmaxf(acc[tp][rg][i] + bv, 0.f));
                    sm[row * 108 + col] = u;
                }
        }
    }
    __syncthreads();

    // pass 2: acc2 = tmp2 @ ew2 (K=128 from LDS; k>=104 clamped to zero)
    f32x4 acc2[2][4];
#pragma unroll
    for (int tp = 0; tp < 2; ++tp)
#pragma unroll
        for (int rg = 0; rg < 4; ++rg) acc2[tp][rg] = (f32x4){0.f, 0.f, 0.f, 0.f};
    bf16x8 ch[2][2], clo[2][2];
    auto loadB2 = [&](int st, int sl) {
        int kk = st * 32 + kgrp * 8;
#pragma unroll
        for (int tp = 0; tp < 2; ++tp) {
            int colw = (w * 2 + tp) * 16 + cl;
            ch[sl][tp]  = *(const bf16x8*)(w2H + (size_t)colw * 128 + kk);
            clo[sl][tp] = *(const bf16x8*)(w2L + (size_t)colw * 128 + kk);
        }
    };
    loadB2(0, 0); loadB2(1, 1);
#pragma unroll
    for (int st = 0; st < 4; ++st) {
        const int sl = st & 1;
#pragma unroll
        for (int rg = 0; rg < 4; ++rg) {
            int row = rg * 16 + cl;
            int kk = st * 32 + kgrp * 8;
            uint4 q0 = make_uint4(0, 0, 0, 0), q1 = make_uint4(0, 0, 0, 0);
            if ((st != 3) || (kgrp == 0)) {
                q0 = *(const uint4*)&sm[row * 108 + kk];
                q1 = *(const uint4*)&sm[row * 108 + kk + 4];
            }
            bf16x8 aH, aL;
            unpack16(q0, q1, aH, aL);
#pragma unroll
            for (int tp = 0; tp < 2; ++tp) {
                acc2[tp][rg] = __builtin_amdgcn_mfma_f32_16x16x32_bf16(aL, ch[sl][tp], acc2[tp][rg], 0, 0, 0);
                acc2[tp][rg] = __builtin_amdgcn_mfma_f32_16x16x32_bf16(aH, clo[sl][tp], acc2[tp][rg], 0, 0, 0);
                acc2[tp][rg] = __builtin_amdgcn_mfma_f32_16x16x32_bf16(aH, ch[sl][tp], acc2[tp][rg], 0, 0, 0);
            }
        }
        if (st + 2 < 4) loadB2(st + 2, sl);
    }
#pragma unroll
    for (int tp = 0; tp < 2; ++tp) {
        int col = (w * 2 + tp) * 16 + cl;
        if (col >= 100) continue;
        float bv = b2v[col];
#pragma unroll
        for (int rg = 0; rg < 4; ++rg)
#pragma unroll
            for (int i = 0; i < 4; ++i) {
                long grow = row0 + rg * 16 + kgrp * 4 + i;
                long o = grow * (long)LDP + col;
                float v = recw(eP[o]) + 0.5f * (acc2[tp][rg][i] + bv);
                eP[o] = packsplit(v);
            }
    }
}

// ---------- fused steps 12+13+14 ----------
__global__ __launch_bounds__(256, 2)
void fused_final_k(const uint* __restrict__ hP, const uint* __restrict__ eP,
                   const ushort* __restrict__ m1H, const ushort* __restrict__ m1L,
                   const float* __restrict__ mb1,
                   const ushort* __restrict__ m2H, const ushort* __restrict__ m2L,
                   const float* __restrict__ mb2, const float* __restrict__ mw3,
                   const float* __restrict__ mb3,
                   const int* __restrict__ g0, const int* __restrict__ g1,
                   const int* __restrict__ eidx, float* __restrict__ out)
{
    __shared__ uint sm[64 * 68];
    const int tid = threadIdx.x, lane = tid & 63, w = tid >> 6;
    const int cl = lane & 15, kgrp = lane >> 4;
    const long row0 = (long)blockIdx.x * 64;

    int rs[4], rd[4];
#pragma unroll
    for (int rg = 0; rg < 4; ++rg) {
        long gr = row0 + rg * 16 + cl;
        rs[rg] = g0[gr]; rd[rg] = g1[gr];
    }

    uint4 aw0[2][4], aw1[2][4];
    bf16x8 bh[2], bl[2];
    f32x4 acc1[4];
#pragma unroll
    for (int rg = 0; rg < 4; ++rg) acc1[rg] = (f32x4){0.f, 0.f, 0.f, 0.f};

    auto loadA = [&](int st, int sl) {
        int seg = st >> 2, inseg = (st & 3) * 32 + kgrp * 8;
        bool ok = ((st & 3) != 3) || (kgrp == 0);
        const uint* base = (seg == 2) ? eP : hP;
#pragma unroll
        for (int rg = 0; rg < 4; ++rg) {
            if (ok) {
                long row = (seg == 0) ? rs[rg] : (seg == 1) ? rd[rg] : (row0 + rg * 16 + cl);
                const uint* p = base + (size_t)row * LDP + inseg;
                aw0[sl][rg] = *(const uint4*)p;
                aw1[sl][rg] = *(const uint4*)(p + 4);
            } else {
                aw0[sl][rg] = make_uint4(0, 0, 0, 0);
                aw1[sl][rg] = make_uint4(0, 0, 0, 0);
            }
        }
    };
    auto loadB = [&](int st, int sl) {
        int kk = st * 32 + kgrp * 8;
        int colw = w * 16 + cl;
        bh[sl] = *(const bf16x8*)(m1H + (size_t)colw * 384 + kk);
        bl[sl] = *(const bf16x8*)(m1L + (size_t)colw * 384 + kk);
    };

    loadA(0, 0); loadB(0, 0); loadA(1, 1); loadB(1, 1);
#pragma unroll
    for (int st = 0; st < 12; ++st) {
        const int sl = st & 1;
#pragma unroll
        for (int rg = 0; rg < 4; ++rg) {
            uint4 w0 = aw0[sl][rg], w1 = aw1[sl][rg];
            if (st < 8) { w0 = relu4(w0); w1 = relu4(w1); }
            bf16x8 aH, aL;
            unpack16(w0, w1, aH, aL);
            acc1[rg] = __builtin_amdgcn_mfma_f32_16x16x32_bf16(aL, bh[sl], acc1[rg], 0, 0, 0);
            acc1[rg] = __builtin_amdgcn_mfma_f32_16x16x32_bf16(aH, bl[sl], acc1[rg], 0, 0, 0);
            acc1[rg] = __builtin_amdgcn_mfma_f32_16x16x32_bf16(aH, bh[sl], acc1[rg], 0, 0, 0);
        }
        if (st + 2 < 12) { loadA(st + 2, sl); loadB(st + 2, sl); }
    }

    {
        int col = w * 16 + cl;
        float bv = (col < 50) ? mb1[col] : 0.f;
#pragma unroll
        for (int rg = 0; rg < 4; ++rg)
#pragma unroll
            for (int i = 0; i < 4; ++i) {
                int row = rg * 16 + kgrp * 4 + i;
                uint u = 0;
                if (col < 50) u = packsplit(fmaxf(acc1[rg][i] + bv, 0.f));
                sm[row * 68 + col] = u;
            }
    }
    __syncthreads();

    bf16x8 c2h[2][2], c2l[2][2];
#pragma unroll
    for (int t = 0; t < 2; ++t)
#pragma unroll
        for (int st = 0; st < 2; ++st) {
            long o = (long)(t * 16 + cl) * 64 + st * 32 + kgrp * 8;
            c2h[t][st] = *(const bf16x8*)(m2H + o);
            c2l[t][st] = *(const bf16x8*)(m2L + o);
        }
    const float bias0 = mb2[cl];
    const float bias1 = (cl + 16 < 25) ? mb2[cl + 16] : 0.f;
    const float w3a0 = mw3[cl * 2 + 0], w3a1 = mw3[cl * 2 + 1];
    const float w3b0 = (cl + 16 < 25) ? mw3[(cl + 16) * 2 + 0] : 0.f;
    const float w3b1 = (cl + 16 < 25) ? mw3[(cl + 16) * 2 + 1] : 0.f;
    const float b30 = mb3[0], b31 = mb3[1];

    const int row = w * 16 + cl;
    f32x4 a0 = (f32x4){0.f, 0.f, 0.f, 0.f}, a1 = a0;
#pragma unroll
    for (int st = 0; st < 2; ++st) {
        int kk = st * 32 + kgrp * 8;
        uint4 q0 = *(const uint4*)&sm[row * 68 + kk];
        uint4 q1 = *(const uint4*)&sm[row * 68 + kk + 4];
        bf16x8 aH, aL;
        unpack16(q0, q1, aH, aL);
        a0 = __builtin_amdgcn_mfma_f32_16x16x32_bf16(aL, c2h[0][st], a0, 0, 0, 0);
        a0 = __builtin_amdgcn_mfma_f32_16x16x32_bf16(aH, c2l[0][st], a0, 0, 0, 0);
        a0 = __builtin_amdgcn_mfma_f32_16x16x32_bf16(aH, c2h[0][st], a0, 0, 0, 0);
        a1 = __builtin_amdgcn_mfma_f32_16x16x32_bf16(aL, c2h[1][st], a1, 0, 0, 0);
        a1 = __builtin_amdgcn_mfma_f32_16x16x32_bf16(aH, c2l[1][st], a1, 0, 0, 0);
        a1 = __builtin_amdgcn_mfma_f32_16x16x32_bf16(aH, c2h[1][st], a1, 0, 0, 0);
    }
#pragma unroll
    for (int i = 0; i < 4; ++i) {
        float t0 = fmaxf(a0[i] + bias0, 0.f);
        float t1 = fmaxf(a1[i] + bias1, 0.f);
        float s0 = t0 * w3a0 + t1 * w3b0;
        float s1 = t0 * w3a1 + t1 * w3b1;
#pragma unroll
        for (int d = 1; d < 16; d <<= 1) {
            s0 += __shfl_xor(s0, d, 64);
            s1 += __shfl_xor(s1, d, 64);
        }
        if (cl == 0) {
            long grow = row0 + w * 16 + kgrp * 4 + i;
            int oe = eidx[grow];
            out[(long)oe * 2 + 0] = s0 + b30;
            out[(long)oe * 2 + 1] = s1 + b31;
        }
    }
}

// ---------- CSR build ----------
__global__ __launch_bounds__(256)
void hist_k(const int* __restrict__ dst, int* __restrict__ cnt)
{
    int e = blockIdx.x * 256 + threadIdx.x;
    if (e < N_EDGES) atomicAdd(&cnt[dst[e]], 1);
}

__global__ __launch_bounds__(1024)
void scan_k(const int* __restrict__ cnt, int* __restrict__ off)
{
    __shared__ int part[1024];
    const int t = threadIdx.x;
    const int per = (N_NODES + 1023) / 1024;
    const int base = t * per;
    int s = 0;
    for (int i = 0; i < per; ++i) {
        int n = base + i;
        if (n < N_NODES) s += cnt[n];
    }
    part[t] = s;
    __syncthreads();
    for (int d = 1; d < 1024; d <<= 1) {
        int v = (t >= d) ? part[t - d] : 0;
        __syncthreads();
        part[t] += v;
        __syncthreads();
    }
    int run = (t == 0) ? 0 : part[t - 1];
    for (int i = 0; i < per; ++i) {
        int n = base + i;
        if (n < N_NODES) { off[n] = run; run += cnt[n]; }
    }
    if (t == 1023) off[N_NODES] = run;
}

__global__ __launch_bounds__(256)
void fill_k(const int* __restrict__ dst, const int* __restrict__ off,
            int* __restrict__ pos, int* __restrict__ eidx)
{
    int e = blockIdx.x * 256 + threadIdx.x;
    if (e >= N_EDGES) return;
    int d = dst[e];
    int p = atomicAdd(&pos[d], 1);
    eidx[off[d] + p] = e;
}

__global__ __launch_bounds__(256)
void perm_k(const int* __restrict__ eidx, const int* __restrict__ src,
            const int* __restrict__ dst, int* __restrict__ psrc, int* __restrict__ pdst)
{
    int j = blockIdx.x * 256 + threadIdx.x;
    if (j >= N_EDGES) return;
    int e = eidx[j];
    psrc[j] = src[e];
    pdst[j] = dst[e];
}

// ---------- aggF = h (fp32, pad cols zero) ----------
__global__ __launch_bounds__(256)
void h2agg_k(const uint* __restrict__ hP, float* __restrict__ aggF)
{
    unsigned idx = blockIdx.x * 256u + threadIdx.x;
    if (idx >= (unsigned)(N_NODES * 26)) return;
    unsigned n = idx / 26u;
    unsigned q = (idx - n * 26u) * 4u;
    long ob = (long)n * TSTR + q;
    if (q >= 100) {
        *(float4*)&aggF[ob] = make_float4(0.f, 0.f, 0.f, 0.f);
        return;
    }
    uint4 hw = *(const uint4*)&hP[(long)n * LDP + q];
    *(float4*)&aggF[ob] = make_float4(recw(hw.x), recw(hw.y), recw(hw.z), recw(hw.w));
}

__global__ __launch_bounds__(128)
void bn_stats_k(const float* __restrict__ z, float* __restrict__ stats)
{
    int c = threadIdx.x;
    if (c >= HDIM) return;
    long rows_per = (N_NODES + gridDim.x - 1) / gridDim.x;
    long r0 = (long)blockIdx.x * rows_per;
    long r1 = r0 + rows_per; if (r1 > N_NODES) r1 = N_NODES;
    float s = 0.f, s2 = 0.f;
    for (long r = r0; r < r1; ++r) {
        float v = z[r * TSTR + c];
        s += v; s2 += v * v;
    }
    atomicAdd(&stats[c], s);
    atomicAdd(&stats[HDIM + c], s2);
}

__global__ __launch_bounds__(256)
void bn_apply_k(const float* __restrict__ z2, const float* __restrict__ stats,
                const float* __restrict__ gamma, const float* __restrict__ beta,
                uint* __restrict__ hP)
{
    unsigned idx = blockIdx.x * 256u + threadIdx.x;
    if (idx >= (unsigned)(N_NODES * 25)) return;
    unsigned n = idx / 25u;
    unsigned q = (idx - n * 25u) * 4u;
    const float invN = 1.f / N_NODES;
    long ob = (long)n * LDP + q;
    uint4 hw = *(const uint4*)&hP[ob];
    float4 zv = *(const float4*)&z2[(long)n * TSTR + q];
    float hv[4] = {recw(hw.x), recw(hw.y), recw(hw.z), recw(hw.w)};
    float zz[4] = {zv.x, zv.y, zv.z, zv.w};
    float r[4];
#pragma unroll
    for (int i = 0; i < 4; ++i) {
        unsigned c = q + i;
        float mu  = stats[c] * invN;
        float var = stats[HDIM + c] * invN - mu * mu;
        float v = (zz[i] - mu) * rsqrtf(var + 1e-5f) * gamma[c] + beta[c];
        r[i] = (hv[i] + fmaxf(v, 0.f)) * 0.5f;
    }
    *(uint4*)&hP[ob] = make_uint4(packsplit(r[0]), packsplit(r[1]), packsplit(r[2]), packsplit(r[3]));
}

static inline int gb64(long m) { return (int)((m + 63) / 64); }

extern "C" void kernel_launch(void* const* d_in, const int* in_sizes, int n_in,
                              void* d_out, int out_size, void* d_ws, size_t ws_size,
                              hipStream_t stream)
{
    const float* x         = (const float*)d_in[0];
    const int*   ei        = (const int*)  d_in[1];
    const float* edge_attr = (const float*)d_in[2];
    const float* node_w    = (const float*)d_in[3];
    const float* node_b    = (const float*)d_in[4];
    const float* edge_w    = (const float*)d_in[5];
    const float* edge_b    = (const float*)d_in[6];
    const float* lin_w     = (const float*)d_in[7];
    const float* lin_b     = (const float*)d_in[8];
    const float* w1        = (const float*)d_in[9];
    const float* b1        = (const float*)d_in[10];
    const float* w2        = (const float*)d_in[11];
    const float* b2        = (const float*)d_in[12];
    const float* gamma     = (const float*)d_in[13];
    const float* beta      = (const float*)d_in[14];
    const float* ew1       = (const float*)d_in[15];
    const float* eb1       = (const float*)d_in[16];
    const float* ew2       = (const float*)d_in[17];
    const float* eb2       = (const float*)d_in[18];
    const float* mw1       = (const float*)d_in[19];
    const float* mb1       = (const float*)d_in[20];
    const float* mw2       = (const float*)d_in[21];
    const float* mb2       = (const float*)d_in[22];
    const float* mw3       = (const float*)d_in[23];
    const float* mb3       = (const float*)d_in[24];
    float* out = (float*)d_out;

    // ---- workspace: [0,2MB) weights | [2MB,16MB) ints+stats | [16MB,..) activations
    ushort* pw = (ushort*)d_ws;
    size_t off_w = 0;
    ushort *nwH, *nwL, *ewH, *ewL, *liH, *liL, *w1H, *w1L, *w2H, *w2L,
           *e1H, *e1L, *e2H, *e2L, *m1H, *m1L, *m2H, *m2L;
    auto nextw = [&](size_t s, ushort*& H, ushort*& L) { H = pw + off_w; L = pw + off_w + s; off_w += 2 * s; };
    nextw(128 * 128,     nwH, nwL);
    nextw(128 * 64,      ewH, ewL);
    nextw(2 * 128 * 128, liH, liL);
    nextw(2 * 128 * 128, w1H, w1L);
    nextw(2 * 128 * 128, w2H, w2L);
    nextw(2 * 128 * 384, e1H, e1L);
    nextw(2 * 128 * 128, e2H, e2L);
    nextw(64 * 384,      m1H, m1L);
    nextw(32 * 64,       m2H, m2L);

    int* intb = (int*)((char*)d_ws + (2u << 20));
    int* cnt   = intb;
    int* coff  = cnt + N_NODES;
    int* pos   = coff + N_NODES + 1;
    int* eidx  = pos + N_NODES;
    int* psrc  = eidx + N_EDGES;
    int* pdst  = psrc + N_EDGES;
    float* stats = (float*)(pdst + N_EDGES);

    char* fbase = (char*)d_ws + (16u << 20);
    uint* eP = (uint*)fbase;                          // E*112 words
    uint* hP = eP + (size_t)N_EDGES * LDP;            // N*112
    uint* zP = hP + (size_t)N_NODES * LDP;            // N*112 (z word planes)
    char* big = (char*)(zP + (size_t)N_NODES * LDP);
    float* aggF = (float*)big;                        // N*104 fp32
    float* z2   = aggF + (size_t)N_NODES * TSTR;      // N*104 fp32

    const int* srcp = ei;
    const int* dstp = ei + N_EDGES;
    dim3 blk(256);

    auto packl = [&](const float* W, ushort* H, ushort* L, int K, int NC, int Kp, int NCp, int batch, bool cc) {
        int total = batch * NCp * Kp;
        if (cc) pack_k<1><<<(total + 255) / 256, blk, 0, stream>>>(W, H, L, K, NC, Kp, NCp, total);
        else    pack_k<0><<<(total + 255) / 256, blk, 0, stream>>>(W, H, L, K, NC, Kp, NCp, total);
    };
    packl(node_w, nwH, nwL, 128, 100, 128, 128, 1, false);
    packl(edge_w, ewH, ewL,  64, 100,  64, 128, 1, false);
    packl(lin_w,  liH, liL, 100, 100, 128, 128, 2, false);
    packl(w1,     w1H, w1L, 100, 100, 128, 128, 2, false);
    packl(w2,     w2H, w2L, 100, 100, 128, 128, 2, false);
    packl(ew1,    e1H, e1L, 300, 100, 384, 128, 2, true);
    packl(ew2,    e2H, e2L, 100, 100, 128, 128, 2, false);
    packl(mw1,    m1H, m1L, 300,  50, 384,  64, 1, true);
    packl(mw2,    m2H, m2L,  50,  25,  64,  32, 1, false);

    hipMemsetAsync(cnt, 0, N_NODES * sizeof(int), stream);
    hist_k<<<(N_EDGES + 255) / 256, blk, 0, stream>>>(dstp, cnt);
    scan_k<<<1, dim3(1024), 0, stream>>>(cnt, coff);
    hipMemsetAsync(pos, 0, N_NODES * sizeof(int), stream);
    fill_k<<<(N_EDGES + 255) / 256, blk, 0, stream>>>(dstp, coff, pos, eidx);
    perm_k<<<(N_EDGES + 255) / 256, blk, 0, stream>>>(eidx, srcp, dstp, psrc, pdst);

    // 1. h = x @ node_w + node_b   (fp32 A, K=128) -> hP
    gemm9_k<8,2,4,0,0,1,0,0><<<gb64(N_NODES), blk, 0, stream>>>(
        nullptr, 0, x, 128, nwH, nwL, node_b, nullptr, hP, LDP, N_NODES, 100, nullptr);
    // 2. e[j] = edge_attr[eidx[j]] @ edge_w + edge_b -> eP
    gemm9_k<8,2,2,0,3,1,0,0><<<gb64(N_EDGES), blk, 0, stream>>>(
        nullptr, 0, edge_attr, 64, ewH, ewL, edge_b, nullptr, eP, LDP, N_EDGES, 100, eidx);

    for (int i = 0; i < 2; ++i) {
        // pre-init aggF = h (covers zero-degree nodes and atomic bases)
        h2agg_k<<<(N_NODES * 26 + 255) / 256, blk, 0, stream>>>(hP, aggF);
        // 3+4+5. fused msg GEMM + segmented aggregate -> aggF
        msg_agg_k<<<gb64(N_EDGES), blk, 0, stream>>>(
            eP, liH + (size_t)i * 16384, liL + (size_t)i * 16384, lin_b + i * HDIM,
            hP, psrc, pdst, aggF);
        // 6. z = relu(aggF @ w1 + b1)  (fp32 A) -> zP words
        gemm9_k<8,2,4,1,0,1,0,0><<<gb64(N_NODES), blk, 0, stream>>>(
            nullptr, 0, aggF, TSTR, w1H + (size_t)i * 16384, w1L + (size_t)i * 16384,
            b1 + i * HDIM, nullptr, zP, LDP, N_NODES, 100, nullptr);
        // 7. z2 = z @ w2 + b2  (word A) -> fp32
        gemm9_k<8,2,4,0,0,0,1,1><<<gb64(N_NODES), blk, 0, stream>>>(
            zP, LDP, nullptr, 0, w2H + (size_t)i * 16384, w2L + (size_t)i * 16384,
            b2 + i * HDIM, z2, nullptr, TSTR, N_NODES, 100, nullptr);
        // 8. BN stats
        hipMemsetAsync(stats, 0, 2 * HDIM * sizeof(float), stream);
        bn_stats_k<<<1024, dim3(128), 0, stream>>>(z2, stats);
        // 9. h = (h + relu(BN(z2)))/2
        bn_apply_k<<<(N_NODES * 25 + 255) / 256, blk, 0, stream>>>(
            z2, stats, gamma + i * HDIM, beta + i * HDIM, hP);
        // 10+11. fused edge update
        fused_edge_k<<<gb64(N_EDGES), blk, 0, stream>>>(
            hP, eP,
            e1H + (size_t)i * 49152, e1L + (size_t)i * 49152, eb1 + i * HDIM,
            e2H + (size_t)i * 16384, e2L + (size_t)i * 16384, eb2 + i * HDIM,
            psrc, pdst);
    }

    // 12+13+14. fused final MLP -> out[eidx]
    fused_final_k<<<gb64(N_EDGES), blk, 0, stream>>>(
        hP, eP, m1H, m1L, mb1, m2H, m2L, mb2, mw3, mb3, psrc, pdst, eidx, out);
}